// Round 5
// baseline (527.996 us; speedup 1.0000x reference)
//
#include <hip/hip_runtime.h>
#include <hip/hip_bf16.h>
#include <cmath>

typedef __hip_bfloat16 bf16;
typedef __attribute__((ext_vector_type(8))) short bf16x8;
typedef __attribute__((ext_vector_type(4))) float f32x4;

static __device__ __forceinline__ float b2f(bf16 v) { return __bfloat162float(v); }
static __device__ __forceinline__ bf16 f2b(float v) { return __float2bfloat16(v); }
static __device__ __forceinline__ float us2f(unsigned short u) {
  return __uint_as_float(((unsigned)u) << 16);
}

static __device__ __forceinline__ void gl2lds16(const bf16* g, bf16* l) {
  __builtin_amdgcn_global_load_lds(
      (const __attribute__((address_space(1))) void*)g,
      (__attribute__((address_space(3))) void*)l, 16, 0, 0);
}

// tanh-form GELU: |err vs erf-form| <~1e-3, far below bf16 rounding of outputs
static __device__ __forceinline__ float gelu_fast(float v) {
  float u = v * (0.7978845608f + 0.0356774081f * v * v);
  float e = __expf(2.f * u);
  return v * (e * __frcp_rn(e + 1.f));
}

// XCD-aware bijective swizzle (m204)
static __device__ __forceinline__ int xcd_swz(int lid, int nwg) {
  const int q = nwg >> 3, r = nwg & 7;
  const int xcd = lid & 7, loc = lid >> 3;
  const int base = (xcd < r) ? xcd * (q + 1) : r * (q + 1) + (xcd - r) * q;
  return base + loc;
}

// ---------------- fused f32 -> bf16 convert for the 7 weight tensors ----------------
struct CvtSegs { const float* src[7]; int blk_off[8]; };
__global__ __launch_bounds__(256) void cvt7_k(CvtSegs s, bf16* __restrict__ dst0)
{
  int b = blockIdx.x;
  int seg = 0;
#pragma unroll
  for (int i = 0; i < 6; ++i) seg += (b >= s.blk_off[i + 1]) ? 1 : 0;
  const float* src = s.src[seg] + (size_t)(b - s.blk_off[seg]) * 1024;
  bf16* dst = dst0 + (size_t)b * 1024;
  int idx = threadIdx.x * 4;
  float4 v = *(const float4*)(src + idx);
  union { bf16 bb[4]; ushort4 u; } o;
  o.bb[0] = f2b(v.x); o.bb[1] = f2b(v.y); o.bb[2] = f2b(v.z); o.bb[3] = f2b(v.w);
  *(ushort4*)(dst + idx) = o.u;
}

__global__ __launch_bounds__(256) void cvt_k(const float* __restrict__ in,
                                             bf16* __restrict__ out, int n)
{
  int idx = (blockIdx.x * 256 + threadIdx.x) * 4;
  if (idx >= n) return;
  float4 v = *(const float4*)(in + idx);
  union { bf16 b[4]; ushort4 u; } o;
  o.b[0] = f2b(v.x); o.b[1] = f2b(v.y); o.b[2] = f2b(v.z); o.b[3] = f2b(v.w);
  *(ushort4*)(out + idx) = o.u;
}

// ---------------- LayerNorm over rows of 1024: f32 in, bf16 out ----------------
__global__ __launch_bounds__(256) void ln_k(const float* __restrict__ X, bf16* __restrict__ Y,
                                            const float* __restrict__ gamma,
                                            const float* __restrict__ beta)
{
  __shared__ float red[16];
  const int row = blockIdx.x, tid = threadIdx.x;
  float4 v = *(const float4*)(X + (size_t)row * 1024 + tid * 4);
  float s  = v.x + v.y + v.z + v.w;
  float s2 = v.x * v.x + v.y * v.y + v.z * v.z + v.w * v.w;
#pragma unroll
  for (int m = 32; m; m >>= 1) { s += __shfl_xor(s, m, 64); s2 += __shfl_xor(s2, m, 64); }
  const int wid = tid >> 6;
  if ((tid & 63) == 0) { red[wid] = s; red[wid + 8] = s2; }
  __syncthreads();
  s  = red[0] + red[1] + red[2] + red[3];
  s2 = red[8] + red[9] + red[10] + red[11];
  const float mu  = s * (1.f / 1024.f);
  const float var = s2 * (1.f / 1024.f) - mu * mu;
  const float rs  = rsqrtf(var + 1e-5f);
  float4 g = *(const float4*)(gamma + tid * 4);
  float4 bt = *(const float4*)(beta + tid * 4);
  union { bf16 b[4]; ushort4 u; } o;
  o.b[0] = f2b((v.x - mu) * rs * g.x + bt.x);
  o.b[1] = f2b((v.y - mu) * rs * g.y + bt.y);
  o.b[2] = f2b((v.z - mu) * rs * g.z + bt.z);
  o.b[3] = f2b((v.w - mu) * rs * g.w + bt.w);
  *(ushort4*)(Y + (size_t)row * 1024 + tid * 4) = o.u;
}

// ============ GEMM 256x256 (8 waves, BK=32, 3-slot, 1 barrier/step, vmcnt(4)) ============
// Same sync structure as the proven gemm_k (stage k+2 into slot 2 barriers away;
// counted vmcnt never 0 in main loop). No manual lgkmcnt(0): compiler interleaves
// ds_read/MFMA with counted lgkm waits so LDS port and matrix pipe overlap at 1 blk/CU.
// LDS slot layout per tensor: [chunk(4)][row(256)][8 bf16] -> ds_read_b128 lanes
// stride 16B within 16-lane groups (0 conflicts, same pattern verified in gemm8p).
__global__ __launch_bounds__(512, 2) void gemm3sa_k(
    const bf16* __restrict__ A, const bf16* __restrict__ W,
    const float* __restrict__ bias, bf16* __restrict__ Out,
    int M, int N, int K)
{
  __shared__ bf16 lds[49152];   // 96KB: A slots @ 0,8192,16384; B slots @ 24576+...
  const int tid = threadIdx.x;
  const int wid = tid >> 6, lane = tid & 63;
  const int quad = lane >> 4, l16 = lane & 15;
  const int wm = wid >> 2, wn = wid & 3;   // 2M x 4N waves, per-wave 128x64

  const int nwg = gridDim.x * gridDim.y;
  int lid = xcd_swz(blockIdx.y * gridDim.x + blockIdx.x, nwg);
  const int bx = lid % gridDim.x, by = lid / gridDim.x;
  const int m0 = by * 256, n0 = bx * 256;

  f32x4 acc[8][4];
#pragma unroll
  for (int i = 0; i < 8; ++i)
#pragma unroll
    for (int j = 0; j < 4; ++j) acc[i][j] = (f32x4){0.f, 0.f, 0.f, 0.f};

  // staging: load r covers chunk 2r+(wid>>2), rows (wid&3)*64+lane
  const bf16 *ga[2], *gb[2];
  int ldso[2];
#pragma unroll
  for (int r = 0; r < 2; ++r) {
    const int row = (wid & 3) * 64 + lane;
    const int ch  = 2 * r + (wid >> 2);
    ga[r] = A + (size_t)(m0 + row) * K + ch * 8;
    gb[r] = W + (size_t)(n0 + row) * K + ch * 8;
    ldso[r] = (r * 512 + wid * 64) * 8;
  }
  const int aofs = quad * 2048 + wm * 1024 + l16 * 8;
  const int bofs = quad * 2048 + wn * 512 + l16 * 8;

  const int niter = K >> 5;

#define STAGE_A(kk, slot)                                                   \
  {                                                                         \
    bf16* asl = lds + (slot) * 8192;                                        \
    bf16* bsl = lds + 24576 + (slot) * 8192;                                \
    _Pragma("unroll")                                                       \
    for (int r = 0; r < 2; ++r) {                                           \
      gl2lds16(ga[r] + (kk) * 32, asl + ldso[r]);                           \
      gl2lds16(gb[r] + (kk) * 32, bsl + ldso[r]);                           \
    }                                                                       \
  }

  STAGE_A(0, 0);
  STAGE_A(1, 1);

  int cur = 0;
  for (int k = 0; k < niter; ++k) {
    if (k == niter - 1) { asm volatile("s_waitcnt vmcnt(0)" ::: "memory"); }
    else               { asm volatile("s_waitcnt vmcnt(4)" ::: "memory"); }
    asm volatile("s_barrier" ::: "memory");

    const bf16* as = lds + cur * 8192;
    const bf16* bs = lds + 24576 + cur * 8192;
    bf16x8 bfr[4], af[8];
#pragma unroll
    for (int nf = 0; nf < 4; ++nf) bfr[nf] = *(const bf16x8*)(bs + bofs + nf * 128);
#pragma unroll
    for (int mf = 0; mf < 8; ++mf) af[mf]  = *(const bf16x8*)(as + aofs + mf * 128);

    if (k + 2 < niter) {
      int nb = cur + 2; if (nb >= 3) nb -= 3;
      STAGE_A(k + 2, nb);
    }
#pragma unroll
    for (int mf = 0; mf < 8; ++mf)
#pragma unroll
      for (int nf = 0; nf < 4; ++nf)
        acc[mf][nf] = __builtin_amdgcn_mfma_f32_16x16x32_bf16(af[mf], bfr[nf], acc[mf][nf], 0, 0, 0);
    cur += 1; if (cur == 3) cur = 0;
  }
#undef STAGE_A

#pragma unroll
  for (int mf = 0; mf < 8; ++mf) {
    const int gm_base = m0 + wm * 128 + mf * 16 + quad * 4;
#pragma unroll
    for (int nf = 0; nf < 4; ++nf) {
      const int gn = n0 + wn * 64 + nf * 16 + l16;
      const float bv = bias[gn];
#pragma unroll
      for (int r = 0; r < 4; ++r) {
        const size_t off = (size_t)(gm_base + r) * N + gn;
        Out[off] = f2b(gelu_fast(acc[mf][nf][r] + bv));
      }
    }
  }
}

// ============ GEMM 256x128 (8 waves 4Mx2N, BK=32, 3-slot, vmcnt(3)) ============
template<int EPI>
__global__ __launch_bounds__(512, 2) void gemm3sb_k(
    const bf16* __restrict__ A, const bf16* __restrict__ W,
    const float* __restrict__ bias, float* __restrict__ Out,
    const float* __restrict__ aux0, const float* __restrict__ aux1,
    int M, int N, int K)
{
  __shared__ bf16 lds[36864];   // 72KB: A slots 3x8192 @0; B slots 3x4096 @24576
  const int tid = threadIdx.x;
  const int wid = tid >> 6, lane = tid & 63;
  const int quad = lane >> 4, l16 = lane & 15;
  const int wm = wid >> 1, wn = wid & 1;   // 4M x 2N waves, per-wave 64x64

  const int nwg = gridDim.x * gridDim.y;
  int lid = xcd_swz(blockIdx.y * gridDim.x + blockIdx.x, nwg);
  const int bx = lid % gridDim.x, by = lid / gridDim.x;
  const int m0 = by * 256, n0 = bx * 128;

  f32x4 acc[4][4];
#pragma unroll
  for (int i = 0; i < 4; ++i)
#pragma unroll
    for (int j = 0; j < 4; ++j) acc[i][j] = (f32x4){0.f, 0.f, 0.f, 0.f};

  const bf16 *ga[2], *gbp;
  int ldsoA[2];
#pragma unroll
  for (int r = 0; r < 2; ++r) {
    const int row = (wid & 3) * 64 + lane;
    const int ch  = 2 * r + (wid >> 2);
    ga[r] = A + (size_t)(m0 + row) * K + ch * 8;
    ldsoA[r] = (r * 512 + wid * 64) * 8;
  }
  gbp = W + (size_t)(n0 + (wid & 1) * 64 + lane) * K + (wid >> 1) * 8;
  const int ldsoB = wid * 512;

  const int aofs = quad * 2048 + wm * 512 + l16 * 8;
  const int bofs = quad * 1024 + wn * 512 + l16 * 8;

  const int niter = K >> 5;

#define STAGE_B(kk, slot)                                                   \
  {                                                                         \
    bf16* asl = lds + (slot) * 8192;                                        \
    bf16* bsl = lds + 24576 + (slot) * 4096;                                \
    _Pragma("unroll")                                                       \
    for (int r = 0; r < 2; ++r)                                             \
      gl2lds16(ga[r] + (kk) * 32, asl + ldsoA[r]);                          \
    gl2lds16(gbp + (kk) * 32, bsl + ldsoB);                                 \
  }

  STAGE_B(0, 0);
  STAGE_B(1, 1);

  int cur = 0;
  for (int k = 0; k < niter; ++k) {
    if (k == niter - 1) { asm volatile("s_waitcnt vmcnt(0)" ::: "memory"); }
    else               { asm volatile("s_waitcnt vmcnt(3)" ::: "memory"); }
    asm volatile("s_barrier" ::: "memory");

    const bf16* as = lds + cur * 8192;
    const bf16* bs = lds + 24576 + cur * 4096;
    bf16x8 bfr[4], af[4];
#pragma unroll
    for (int nf = 0; nf < 4; ++nf) bfr[nf] = *(const bf16x8*)(bs + bofs + nf * 128);
#pragma unroll
    for (int mf = 0; mf < 4; ++mf) af[mf]  = *(const bf16x8*)(as + aofs + mf * 128);

    if (k + 2 < niter) {
      int nb = cur + 2; if (nb >= 3) nb -= 3;
      STAGE_B(k + 2, nb);
    }
#pragma unroll
    for (int mf = 0; mf < 4; ++mf)
#pragma unroll
      for (int nf = 0; nf < 4; ++nf)
        acc[mf][nf] = __builtin_amdgcn_mfma_f32_16x16x32_bf16(af[mf], bfr[nf], acc[mf][nf], 0, 0, 0);
    cur += 1; if (cur == 3) cur = 0;
  }
#undef STAGE_B

#pragma unroll
  for (int mf = 0; mf < 4; ++mf) {
    const int gm_base = m0 + wm * 64 + mf * 16 + quad * 4;
#pragma unroll
    for (int nf = 0; nf < 4; ++nf) {
      const int gn = n0 + wn * 64 + nf * 16 + l16;
      const float bv = bias[gn];
#pragma unroll
      for (int r = 0; r < 4; ++r) {
        const size_t off = (size_t)(gm_base + r) * N + gn;
        float v = acc[mf][nf][r] + bv;
        if (EPI == 2) Out[off] = v * aux0[off] + aux1[off];
        else          Out[off] = v + aux0[off];
      }
    }
  }
}

// ================= GEMM 128x128 (4 waves, 3-stage async, XCD-swizzled) =================
template<int EPI>
__global__ __launch_bounds__(256, 3) void gemm_k(
    const bf16* __restrict__ A, const bf16* __restrict__ W,
    const float* __restrict__ bias, void* __restrict__ Out,
    const void* __restrict__ aux0, const void* __restrict__ aux1,
    int M, int N, int K)
{
  __shared__ bf16 As[3][128 * 32];
  __shared__ bf16 Bs[3][128 * 32];
  const int tid = threadIdx.x;
  const int wid = tid >> 6, lane = tid & 63;
  const int quad = lane >> 4, l16 = lane & 15;
  const int wm = wid >> 1, wn = wid & 1;

  const int nwg = gridDim.x * gridDim.y;
  int lid = xcd_swz(blockIdx.y * gridDim.x + blockIdx.x, nwg);
  const int bx = lid % gridDim.x, by = lid / gridDim.x;
  const int m0 = by * 128, n0 = bx * 128;

  f32x4 acc[4][4];
#pragma unroll
  for (int i = 0; i < 4; ++i)
#pragma unroll
    for (int j = 0; j < 4; ++j) acc[i][j] = (f32x4){0.f, 0.f, 0.f, 0.f};

  const bf16 *ga[2], *gb[2];
  int ldso[2];
#pragma unroll
  for (int r = 0; r < 2; ++r) {
    int p = r * 256 + wid * 64 + lane;
    int row = p >> 2;
    int sko = ((p & 3) ^ ((p >> 3) & 3)) << 3;
    ga[r] = A + (size_t)(m0 + row) * K + sko;
    gb[r] = W + (size_t)(n0 + row) * K + sko;
    ldso[r] = (r * 256 + wid * 64) * 8;
  }
  int apos[4], bpos[4];
#pragma unroll
  for (int i = 0; i < 4; ++i) {
    int ar = wm * 64 + i * 16 + l16;
    apos[i] = (ar * 4 + (quad ^ ((ar >> 1) & 3))) * 8;
    int br = wn * 64 + i * 16 + l16;
    bpos[i] = (br * 4 + (quad ^ ((br >> 1) & 3))) * 8;
  }

  const int niter = K >> 5;
#pragma unroll
  for (int t = 0; t < 2; ++t)
#pragma unroll
    for (int r = 0; r < 2; ++r) {
      gl2lds16(ga[r] + t * 32, &As[t][ldso[r]]);
      gl2lds16(gb[r] + t * 32, &Bs[t][ldso[r]]);
    }

  int cur = 0;
  for (int k = 0; k < niter; ++k) {
    if (k == niter - 1) { asm volatile("s_waitcnt vmcnt(0)" ::: "memory"); }
    else               { asm volatile("s_waitcnt vmcnt(4)" ::: "memory"); }
    asm volatile("s_barrier" ::: "memory");

    const bf16* as = As[cur];
    const bf16* bs = Bs[cur];
    bf16x8 af[4], bfr[4];
#pragma unroll
    for (int i = 0; i < 4; ++i) af[i]  = *(const bf16x8*)(as + apos[i]);
#pragma unroll
    for (int j = 0; j < 4; ++j) bfr[j] = *(const bf16x8*)(bs + bpos[j]);
    asm volatile("s_waitcnt lgkmcnt(0)" ::: "memory");

    if (k + 2 < niter) {
      int nb = cur + 2; if (nb >= 3) nb -= 3;
#pragma unroll
      for (int r = 0; r < 2; ++r) {
        gl2lds16(ga[r] + (k + 2) * 32, &As[nb][ldso[r]]);
        gl2lds16(gb[r] + (k + 2) * 32, &Bs[nb][ldso[r]]);
      }
    }
#pragma unroll
    for (int i = 0; i < 4; ++i)
#pragma unroll
      for (int j = 0; j < 4; ++j)
        acc[i][j] = __builtin_amdgcn_mfma_f32_16x16x32_bf16(af[i], bfr[j], acc[i][j], 0, 0, 0);
    cur += 1; if (cur == 3) cur = 0;
  }

  float expa = 0.f;
  if (EPI == 1) expa = expf(((const float*)aux0)[0]);
#pragma unroll
  for (int i = 0; i < 4; ++i) {
    const int gm_base = m0 + wm * 64 + i * 16 + quad * 4;
#pragma unroll
    for (int j = 0; j < 4; ++j) {
      const int gn = n0 + wn * 64 + j * 16 + l16;
      const float bv = bias[gn];
#pragma unroll
      for (int r = 0; r < 4; ++r) {
        const int gm = gm_base + r;
        const size_t off = (size_t)gm * N + gn;
        float v = acc[i][j][r] + bv;
        if (EPI == 0) ((bf16*)Out)[off] = f2b(gelu_fast(v));
        else if (EPI == 1) ((float*)Out)[off] = v * expf(-(float)gm * expa);
        else if (EPI == 2) ((float*)Out)[off] = v * ((const float*)aux0)[off] + ((const float*)aux1)[off];
        else ((float*)Out)[off] = v + ((const float*)aux0)[off];
      }
    }
  }
}

// ---------------- causal depthwise conv ----------------
__global__ __launch_bounds__(256) void conv_k(
    const bf16* __restrict__ zn,    // [B, L, D] bf16
    const float* __restrict__ wh,   // [L, D] f32
    const float* __restrict__ a,
    float* __restrict__ out)        // [B, L, D] f32
{
  __shared__ float whs[64 * 64];
  __shared__ float znt[128 * 64];   // row r holds u = t0 - sb - 64 + r
  const int tid = threadIdx.x;
  const int dd = tid & 63, ttg = tid >> 6;
  const int t0 = blockIdx.x * 64, d0 = blockIdx.y * 64, b = blockIdx.z;
  const float expa = expf(a[0]);
  const float smax = 20.7f / expa;
  const unsigned short* znu = (const unsigned short*)zn;

  float acc[16];
#pragma unroll
  for (int q = 0; q < 16; ++q) acc[q] = 0.f;

  for (int sb = 0; sb <= t0 + 63; sb += 64) {
    if ((float)sb > smax) break;
    float4 wv4[4];
#pragma unroll
    for (int i = 0; i < 4; ++i) {
      int cc = tid + 256 * i;
      int row = cc >> 4, dq = (cc & 15) * 4;
      wv4[i] = *(const float4*)&wh[(size_t)(sb + row) * 1024 + d0 + dq];
    }
    ushort4 zv4[8];
#pragma unroll
    for (int i = 0; i < 8; ++i) {
      int cc = tid + 256 * i;
      int row = cc >> 4, dq = (cc & 15) * 4;
      int u = t0 - sb - 64 + row;
      zv4[i] = (u >= 0) ? *(const ushort4*)&znu[((size_t)b * 2048 + u) * 1024 + d0 + dq]
                        : make_ushort4(0, 0, 0, 0);
    }
#pragma unroll
    for (int i = 0; i < 4; ++i) {
      int cc = tid + 256 * i;
      *(float4*)&whs[(cc >> 4) * 64 + (cc & 15) * 4] = wv4[i];
    }
#pragma unroll
    for (int i = 0; i < 8; ++i) {
      int cc = tid + 256 * i;
      float4 o;
      o.x = us2f(zv4[i].x); o.y = us2f(zv4[i].y); o.z = us2f(zv4[i].z); o.w = us2f(zv4[i].w);
      *(float4*)&znt[(cc >> 4) * 64 + (cc & 15) * 4] = o;
    }
    __syncthreads();

    float win[16];
#pragma unroll
    for (int q = 0; q < 16; ++q) win[q] = znt[(ttg * 16 + q + 64) * 64 + dd];
#pragma unroll
    for (int ss = 0; ss < 64; ++ss) {
      float wv = whs[ss * 64 + dd];
#pragma unroll
      for (int q = 0; q < 16; ++q) acc[q] += wv * win[q];
      if (ss < 63) {
#pragma unroll
        for (int q = 15; q >= 1; --q) win[q] = win[q - 1];
        win[0] = znt[(ttg * 16 + 63 - ss) * 64 + dd];
      }
    }
    __syncthreads();
  }
#pragma unroll
  for (int q = 0; q < 16; ++q) {
    int t = t0 + ttg * 16 + q;
    out[((size_t)b * 2048 + t) * 1024 + d0 + dd] = acc[q];
  }
}

extern "C" void kernel_launch(void* const* d_in, const int* in_sizes, int n_in,
                              void* d_out, int out_size, void* d_ws, size_t ws_size,
                              hipStream_t stream)
{
  const float* z      = (const float*)d_in[0];
  const float* x      = (const float*)d_in[1];
  const float* a      = (const float*)d_in[2];
  const float* pe     = (const float*)d_in[3];
  const float* w_pos1 = (const float*)d_in[4];
  const float* b_pos1 = (const float*)d_in[5];
  const float* w_pos2 = (const float*)d_in[6];
  const float* b_pos2 = (const float*)d_in[7];
  const float* w1     = (const float*)d_in[8];
  const float* b1     = (const float*)d_in[9];
  const float* w2     = (const float*)d_in[10];
  const float* b2     = (const float*)d_in[11];
  const float* w3     = (const float*)d_in[12];
  const float* b3     = (const float*)d_in[13];
  const float* w4     = (const float*)d_in[14];
  const float* b4     = (const float*)d_in[15];
  const float* ln_g   = (const float*)d_in[16];
  const float* ln_b   = (const float*)d_in[17];

  char* ws = (char*)d_ws;
  bf16* pe_bf  = (bf16*)(ws + 0);
  bf16* wp1_bf = (bf16*)(ws + 524288);
  bf16* wp2_bf = (bf16*)(ws + 819200);
  bf16* w1_bf  = (bf16*)(ws + 3178496);
  bf16* w2_bf  = (bf16*)(ws + 7372800);
  bf16* w3_bf  = (bf16*)(ws + 11567104);
  bf16* w4_bf  = (bf16*)(ws + 15761408);
  bf16* h1     = (bf16*)(ws + 19955712);
  bf16* zn_bf  = (bf16*)(ws + 24674304);
  bf16* x_bf   = (bf16*)(ws + 41451520);
  float* wh    = (float*)(ws + 58228736);
  float* cwhz  = (float*)(ws + 66617344);
  bf16*  x1n   = (bf16*)(ws + 66617344);
  bf16*  g     = (bf16*)(ws + 100171776);
  float* x1    = (float*)(ws + 24674304);
  float* out   = (float*)d_out;

  CvtSegs segs;
  segs.src[0] = pe;  segs.src[1] = w_pos1; segs.src[2] = w_pos2;
  segs.src[3] = w1;  segs.src[4] = w2;     segs.src[5] = w3; segs.src[6] = w4;
  int bo[8] = {0, 256, 400, 1552, 3600, 5648, 7696, 9744};
  for (int i = 0; i < 8; ++i) segs.blk_off[i] = bo[i];
  cvt7_k<<<9744, 256, 0, stream>>>(segs, (bf16*)ws);
  cvt_k<<<8192, 256, 0, stream>>>(x, x_bf, 8388608);

  // 1. zn = LN(z) -> bf16
  ln_k<<<8192, 256, 0, stream>>>(z, zn_bf, ln_g, ln_b);
  // 2. h1 = gelu(pe @ w_pos1^T + b_pos1) -> bf16   [2048, 1152], K=128
  gemm_k<0><<<dim3(9, 16), 256, 0, stream>>>(pe_bf, wp1_bf, b_pos1, h1, nullptr, nullptr, 2048, 1152, 128);
  // 3. wh = window * (h1 @ w_pos2^T + b_pos2) f32  [2048, 1024], K=1152
  gemm_k<1><<<dim3(8, 16), 256, 0, stream>>>(h1, wp2_bf, b_pos2, wh, a, nullptr, 2048, 1024, 1152);
  // 4. cwhz = causal depthwise conv(zn, wh) f32    [4, 2048, 1024]
  conv_k<<<dim3(32, 16, 4), 256, 0, stream>>>(zn_bf, wh, a, cwhz);
  // 5. g1 = gelu(x @ w1^T + b1) -> bf16            [8192, 2048], K=1024
  gemm3sa_k<<<dim3(8, 32), 512, 0, stream>>>(x_bf, w1_bf, b1, g, 8192, 2048, 1024);
  // 6. x1 = (g1 @ w2^T + b2) * cwhz + z   f32      [8192, 1024], K=2048
  gemm3sb_k<2><<<dim3(8, 32), 512, 0, stream>>>(g, w2_bf, b2, x1, cwhz, z, 8192, 1024, 2048);
  // 7. x1n = LN(x1) -> bf16
  ln_k<<<8192, 256, 0, stream>>>(x1, x1n, ln_g, ln_b);
  // 8. g3 = gelu(x1n @ w3^T + b3) -> bf16          [8192, 2048], K=1024
  gemm3sa_k<<<dim3(8, 32), 512, 0, stream>>>(x1n, w3_bf, b3, g, 8192, 2048, 1024);
  // 9. out = (g3 @ w4^T + b4) + x1  f32            [8192, 1024], K=2048
  gemm3sb_k<3><<<dim3(8, 32), 512, 0, stream>>>(g, w4_bf, b4, out, x1, nullptr, 8192, 1024, 2048);
}

// Round 6
// 444.251 us; speedup vs baseline: 1.1885x; 1.1885x over previous
//
#include <hip/hip_runtime.h>
#include <hip/hip_bf16.h>
#include <cmath>

typedef __hip_bfloat16 bf16;
typedef __attribute__((ext_vector_type(8))) short bf16x8;
typedef __attribute__((ext_vector_type(4))) float f32x4;

static __device__ __forceinline__ float b2f(bf16 v) { return __bfloat162float(v); }
static __device__ __forceinline__ bf16 f2b(float v) { return __float2bfloat16(v); }
static __device__ __forceinline__ float us2f(unsigned short u) {
  return __uint_as_float(((unsigned)u) << 16);
}

static __device__ __forceinline__ void gl2lds16(const bf16* g, bf16* l) {
  __builtin_amdgcn_global_load_lds(
      (const __attribute__((address_space(1))) void*)g,
      (__attribute__((address_space(3))) void*)l, 16, 0, 0);
}

// tanh-form GELU: |err vs erf-form| <~1e-3, far below bf16 rounding of outputs
static __device__ __forceinline__ float gelu_fast(float v) {
  float u = v * (0.7978845608f + 0.0356774081f * v * v);
  float e = __expf(2.f * u);
  return v * (e * __frcp_rn(e + 1.f));
}

// XCD-aware bijective swizzle (m204)
static __device__ __forceinline__ int xcd_swz(int lid, int nwg) {
  const int q = nwg >> 3, r = nwg & 7;
  const int xcd = lid & 7, loc = lid >> 3;
  const int base = (xcd < r) ? xcd * (q + 1) : r * (q + 1) + (xcd - r) * q;
  return base + loc;
}

// ---------------- fused f32 -> bf16 convert for the 7 weight tensors ----------------
struct CvtSegs { const float* src[7]; int blk_off[8]; };
__global__ __launch_bounds__(256) void cvt7_k(CvtSegs s, bf16* __restrict__ dst0)
{
  int b = blockIdx.x;
  int seg = 0;
#pragma unroll
  for (int i = 0; i < 6; ++i) seg += (b >= s.blk_off[i + 1]) ? 1 : 0;
  const float* src = s.src[seg] + (size_t)(b - s.blk_off[seg]) * 1024;
  bf16* dst = dst0 + (size_t)b * 1024;
  int idx = threadIdx.x * 4;
  float4 v = *(const float4*)(src + idx);
  union { bf16 bb[4]; ushort4 u; } o;
  o.bb[0] = f2b(v.x); o.bb[1] = f2b(v.y); o.bb[2] = f2b(v.z); o.bb[3] = f2b(v.w);
  *(ushort4*)(dst + idx) = o.u;
}

__global__ __launch_bounds__(256) void cvt_k(const float* __restrict__ in,
                                             bf16* __restrict__ out, int n)
{
  int idx = (blockIdx.x * 256 + threadIdx.x) * 4;
  if (idx >= n) return;
  float4 v = *(const float4*)(in + idx);
  union { bf16 b[4]; ushort4 u; } o;
  o.b[0] = f2b(v.x); o.b[1] = f2b(v.y); o.b[2] = f2b(v.z); o.b[3] = f2b(v.w);
  *(ushort4*)(out + idx) = o.u;
}

// ---------------- LayerNorm over rows of 1024: f32 in, bf16 out ----------------
__global__ __launch_bounds__(256) void ln_k(const float* __restrict__ X, bf16* __restrict__ Y,
                                            const float* __restrict__ gamma,
                                            const float* __restrict__ beta)
{
  __shared__ float red[16];
  const int row = blockIdx.x, tid = threadIdx.x;
  float4 v = *(const float4*)(X + (size_t)row * 1024 + tid * 4);
  float s  = v.x + v.y + v.z + v.w;
  float s2 = v.x * v.x + v.y * v.y + v.z * v.z + v.w * v.w;
#pragma unroll
  for (int m = 32; m; m >>= 1) { s += __shfl_xor(s, m, 64); s2 += __shfl_xor(s2, m, 64); }
  const int wid = tid >> 6;
  if ((tid & 63) == 0) { red[wid] = s; red[wid + 8] = s2; }
  __syncthreads();
  s  = red[0] + red[1] + red[2] + red[3];
  s2 = red[8] + red[9] + red[10] + red[11];
  const float mu  = s * (1.f / 1024.f);
  const float var = s2 * (1.f / 1024.f) - mu * mu;
  const float rs  = rsqrtf(var + 1e-5f);
  float4 g = *(const float4*)(gamma + tid * 4);
  float4 bt = *(const float4*)(beta + tid * 4);
  union { bf16 b[4]; ushort4 u; } o;
  o.b[0] = f2b((v.x - mu) * rs * g.x + bt.x);
  o.b[1] = f2b((v.y - mu) * rs * g.y + bt.y);
  o.b[2] = f2b((v.z - mu) * rs * g.z + bt.z);
  o.b[3] = f2b((v.w - mu) * rs * g.w + bt.w);
  *(ushort4*)(Y + (size_t)row * 1024 + tid * 4) = o.u;
}

// ================= GEMM 128x128 (4 waves, 3-stage async, XCD-swizzled) =================
// Verified structure: 1 barrier/step, counted vmcnt, batched ds_read + lgkmcnt(0).
template<int EPI>
__global__ __launch_bounds__(256, 3) void gemm_k(
    const bf16* __restrict__ A, const bf16* __restrict__ W,
    const float* __restrict__ bias, void* __restrict__ Out,
    const void* __restrict__ aux0, const void* __restrict__ aux1,
    int M, int N, int K)
{
  __shared__ bf16 As[3][128 * 32];
  __shared__ bf16 Bs[3][128 * 32];
  const int tid = threadIdx.x;
  const int wid = tid >> 6, lane = tid & 63;
  const int quad = lane >> 4, l16 = lane & 15;
  const int wm = wid >> 1, wn = wid & 1;

  const int nwg = gridDim.x * gridDim.y;
  int lid = xcd_swz(blockIdx.y * gridDim.x + blockIdx.x, nwg);
  const int bx = lid % gridDim.x, by = lid / gridDim.x;
  const int m0 = by * 128, n0 = bx * 128;

  f32x4 acc[4][4];
#pragma unroll
  for (int i = 0; i < 4; ++i)
#pragma unroll
    for (int j = 0; j < 4; ++j) acc[i][j] = (f32x4){0.f, 0.f, 0.f, 0.f};

  const bf16 *ga[2], *gb[2];
  int ldso[2];
#pragma unroll
  for (int r = 0; r < 2; ++r) {
    int p = r * 256 + wid * 64 + lane;
    int row = p >> 2;
    int sko = ((p & 3) ^ ((p >> 3) & 3)) << 3;
    ga[r] = A + (size_t)(m0 + row) * K + sko;
    gb[r] = W + (size_t)(n0 + row) * K + sko;
    ldso[r] = (r * 256 + wid * 64) * 8;
  }
  int apos[4], bpos[4];
#pragma unroll
  for (int i = 0; i < 4; ++i) {
    int ar = wm * 64 + i * 16 + l16;
    apos[i] = (ar * 4 + (quad ^ ((ar >> 1) & 3))) * 8;
    int br = wn * 64 + i * 16 + l16;
    bpos[i] = (br * 4 + (quad ^ ((br >> 1) & 3))) * 8;
  }

  const int niter = K >> 5;
#pragma unroll
  for (int t = 0; t < 2; ++t)
#pragma unroll
    for (int r = 0; r < 2; ++r) {
      gl2lds16(ga[r] + t * 32, &As[t][ldso[r]]);
      gl2lds16(gb[r] + t * 32, &Bs[t][ldso[r]]);
    }

  int cur = 0;
  for (int k = 0; k < niter; ++k) {
    if (k == niter - 1) { asm volatile("s_waitcnt vmcnt(0)" ::: "memory"); }
    else               { asm volatile("s_waitcnt vmcnt(4)" ::: "memory"); }
    asm volatile("s_barrier" ::: "memory");

    const bf16* as = As[cur];
    const bf16* bs = Bs[cur];
    bf16x8 af[4], bfr[4];
#pragma unroll
    for (int i = 0; i < 4; ++i) af[i]  = *(const bf16x8*)(as + apos[i]);
#pragma unroll
    for (int j = 0; j < 4; ++j) bfr[j] = *(const bf16x8*)(bs + bpos[j]);
    asm volatile("s_waitcnt lgkmcnt(0)" ::: "memory");

    if (k + 2 < niter) {
      int nb = cur + 2; if (nb >= 3) nb -= 3;
#pragma unroll
      for (int r = 0; r < 2; ++r) {
        gl2lds16(ga[r] + (k + 2) * 32, &As[nb][ldso[r]]);
        gl2lds16(gb[r] + (k + 2) * 32, &Bs[nb][ldso[r]]);
      }
    }
#pragma unroll
    for (int i = 0; i < 4; ++i)
#pragma unroll
      for (int j = 0; j < 4; ++j)
        acc[i][j] = __builtin_amdgcn_mfma_f32_16x16x32_bf16(af[i], bfr[j], acc[i][j], 0, 0, 0);
    cur += 1; if (cur == 3) cur = 0;
  }

  float expa = 0.f;
  if (EPI == 1) expa = expf(((const float*)aux0)[0]);
#pragma unroll
  for (int i = 0; i < 4; ++i) {
    const int gm_base = m0 + wm * 64 + i * 16 + quad * 4;
#pragma unroll
    for (int j = 0; j < 4; ++j) {
      const int gn = n0 + wn * 64 + j * 16 + l16;
      const float bv = bias[gn];
#pragma unroll
      for (int r = 0; r < 4; ++r) {
        const int gm = gm_base + r;
        const size_t off = (size_t)gm * N + gn;
        float v = acc[i][j][r] + bv;
        if (EPI == 0) ((bf16*)Out)[off] = f2b(gelu_fast(v));
        else if (EPI == 1) ((float*)Out)[off] = v * expf(-(float)gm * expa);
        else if (EPI == 2) ((float*)Out)[off] = v * ((const float*)aux0)[off] + ((const float*)aux1)[off];
        else ((float*)Out)[off] = v + ((const float*)aux0)[off];
      }
    }
  }
}

// ================= GEMM 128x64 (4 waves, same structure, 36KB LDS -> 4 blocks/CU) =======
// Identical sync/swizzle algebra to gemm_k; B-side halved. 3 loads/thread/step -> vmcnt(3).
template<int EPI>
__global__ __launch_bounds__(256, 4) void gemm64_k(
    const bf16* __restrict__ A, const bf16* __restrict__ W,
    const float* __restrict__ bias, void* __restrict__ Out,
    const void* __restrict__ aux0, const void* __restrict__ aux1,
    int M, int N, int K)
{
  __shared__ bf16 As[3][128 * 32];
  __shared__ bf16 Bs[3][64 * 32];
  const int tid = threadIdx.x;
  const int wid = tid >> 6, lane = tid & 63;
  const int quad = lane >> 4, l16 = lane & 15;
  const int wm = wid >> 1, wn = wid & 1;

  const int nwg = gridDim.x * gridDim.y;
  int lid = xcd_swz(blockIdx.y * gridDim.x + blockIdx.x, nwg);
  const int bx = lid % gridDim.x, by = lid / gridDim.x;
  const int m0 = by * 128, n0 = bx * 64;

  f32x4 acc[4][2];
#pragma unroll
  for (int i = 0; i < 4; ++i)
#pragma unroll
    for (int j = 0; j < 2; ++j) acc[i][j] = (f32x4){0.f, 0.f, 0.f, 0.f};

  const bf16 *ga[2], *gbp;
  int ldsoA[2];
#pragma unroll
  for (int r = 0; r < 2; ++r) {
    int p = r * 256 + wid * 64 + lane;
    int row = p >> 2;
    int sko = ((p & 3) ^ ((p >> 3) & 3)) << 3;
    ga[r] = A + (size_t)(m0 + row) * K + sko;
    ldsoA[r] = (r * 256 + wid * 64) * 8;
  }
  {
    int p = wid * 64 + lane;           // 0..255 covers 64 rows x 4 chunks
    int row = p >> 2;
    int sko = ((p & 3) ^ ((p >> 3) & 3)) << 3;
    gbp = W + (size_t)(n0 + row) * K + sko;
  }
  const int ldsoB = wid * 64 * 8;

  int apos[4], bpos[2];
#pragma unroll
  for (int i = 0; i < 4; ++i) {
    int ar = wm * 64 + i * 16 + l16;
    apos[i] = (ar * 4 + (quad ^ ((ar >> 1) & 3))) * 8;
  }
#pragma unroll
  for (int j = 0; j < 2; ++j) {
    int br = wn * 32 + j * 16 + l16;
    bpos[j] = (br * 4 + (quad ^ ((br >> 1) & 3))) * 8;
  }

  const int niter = K >> 5;
#pragma unroll
  for (int t = 0; t < 2; ++t) {
#pragma unroll
    for (int r = 0; r < 2; ++r) gl2lds16(ga[r] + t * 32, &As[t][ldsoA[r]]);
    gl2lds16(gbp + t * 32, &Bs[t][ldsoB]);
  }

  int cur = 0;
  for (int k = 0; k < niter; ++k) {
    if (k == niter - 1) { asm volatile("s_waitcnt vmcnt(0)" ::: "memory"); }
    else               { asm volatile("s_waitcnt vmcnt(3)" ::: "memory"); }
    asm volatile("s_barrier" ::: "memory");

    const bf16* as = As[cur];
    const bf16* bs = Bs[cur];
    bf16x8 af[4], bfr[2];
#pragma unroll
    for (int i = 0; i < 4; ++i) af[i]  = *(const bf16x8*)(as + apos[i]);
#pragma unroll
    for (int j = 0; j < 2; ++j) bfr[j] = *(const bf16x8*)(bs + bpos[j]);
    asm volatile("s_waitcnt lgkmcnt(0)" ::: "memory");

    if (k + 2 < niter) {
      int nb = cur + 2; if (nb >= 3) nb -= 3;
#pragma unroll
      for (int r = 0; r < 2; ++r) gl2lds16(ga[r] + (k + 2) * 32, &As[nb][ldsoA[r]]);
      gl2lds16(gbp + (k + 2) * 32, &Bs[nb][ldsoB]);
    }
#pragma unroll
    for (int i = 0; i < 4; ++i)
#pragma unroll
      for (int j = 0; j < 2; ++j)
        acc[i][j] = __builtin_amdgcn_mfma_f32_16x16x32_bf16(af[i], bfr[j], acc[i][j], 0, 0, 0);
    cur += 1; if (cur == 3) cur = 0;
  }

  float expa = 0.f;
  if (EPI == 1) expa = expf(((const float*)aux0)[0]);
#pragma unroll
  for (int i = 0; i < 4; ++i) {
    const int gm_base = m0 + wm * 64 + i * 16 + quad * 4;
#pragma unroll
    for (int j = 0; j < 2; ++j) {
      const int gn = n0 + wn * 32 + j * 16 + l16;
      const float bv = bias[gn];
#pragma unroll
      for (int r = 0; r < 4; ++r) {
        const int gm = gm_base + r;
        const size_t off = (size_t)gm * N + gn;
        float v = acc[i][j][r] + bv;
        if (EPI == 0) ((bf16*)Out)[off] = f2b(gelu_fast(v));
        else if (EPI == 1) ((float*)Out)[off] = v * expf(-(float)gm * expa);
        else if (EPI == 2) ((float*)Out)[off] = v * ((const float*)aux0)[off] + ((const float*)aux1)[off];
        else ((float*)Out)[off] = v + ((const float*)aux0)[off];
      }
    }
  }
}

// ---------------- causal depthwise conv ----------------
__global__ __launch_bounds__(256) void conv_k(
    const bf16* __restrict__ zn,    // [B, L, D] bf16
    const float* __restrict__ wh,   // [L, D] f32
    const float* __restrict__ a,
    float* __restrict__ out)        // [B, L, D] f32
{
  __shared__ float whs[64 * 64];
  __shared__ float znt[128 * 64];   // row r holds u = t0 - sb - 64 + r
  const int tid = threadIdx.x;
  const int dd = tid & 63, ttg = tid >> 6;
  const int t0 = blockIdx.x * 64, d0 = blockIdx.y * 64, b = blockIdx.z;
  const float expa = expf(a[0]);
  const float smax = 20.7f / expa;
  const unsigned short* znu = (const unsigned short*)zn;

  float acc[16];
#pragma unroll
  for (int q = 0; q < 16; ++q) acc[q] = 0.f;

  for (int sb = 0; sb <= t0 + 63; sb += 64) {
    if ((float)sb > smax) break;
    float4 wv4[4];
#pragma unroll
    for (int i = 0; i < 4; ++i) {
      int cc = tid + 256 * i;
      int row = cc >> 4, dq = (cc & 15) * 4;
      wv4[i] = *(const float4*)&wh[(size_t)(sb + row) * 1024 + d0 + dq];
    }
    ushort4 zv4[8];
#pragma unroll
    for (int i = 0; i < 8; ++i) {
      int cc = tid + 256 * i;
      int row = cc >> 4, dq = (cc & 15) * 4;
      int u = t0 - sb - 64 + row;
      zv4[i] = (u >= 0) ? *(const ushort4*)&znu[((size_t)b * 2048 + u) * 1024 + d0 + dq]
                        : make_ushort4(0, 0, 0, 0);
    }
#pragma unroll
    for (int i = 0; i < 4; ++i) {
      int cc = tid + 256 * i;
      *(float4*)&whs[(cc >> 4) * 64 + (cc & 15) * 4] = wv4[i];
    }
#pragma unroll
    for (int i = 0; i < 8; ++i) {
      int cc = tid + 256 * i;
      float4 o;
      o.x = us2f(zv4[i].x); o.y = us2f(zv4[i].y); o.z = us2f(zv4[i].z); o.w = us2f(zv4[i].w);
      *(float4*)&znt[(cc >> 4) * 64 + (cc & 15) * 4] = o;
    }
    __syncthreads();

    float win[16];
#pragma unroll
    for (int q = 0; q < 16; ++q) win[q] = znt[(ttg * 16 + q + 64) * 64 + dd];
#pragma unroll
    for (int ss = 0; ss < 64; ++ss) {
      float wv = whs[ss * 64 + dd];
#pragma unroll
      for (int q = 0; q < 16; ++q) acc[q] += wv * win[q];
      if (ss < 63) {
#pragma unroll
        for (int q = 15; q >= 1; --q) win[q] = win[q - 1];
        win[0] = znt[(ttg * 16 + 63 - ss) * 64 + dd];
      }
    }
    __syncthreads();
  }
#pragma unroll
  for (int q = 0; q < 16; ++q) {
    int t = t0 + ttg * 16 + q;
    out[((size_t)b * 2048 + t) * 1024 + d0 + dd] = acc[q];
  }
}

extern "C" void kernel_launch(void* const* d_in, const int* in_sizes, int n_in,
                              void* d_out, int out_size, void* d_ws, size_t ws_size,
                              hipStream_t stream)
{
  const float* z      = (const float*)d_in[0];
  const float* x      = (const float*)d_in[1];
  const float* a      = (const float*)d_in[2];
  const float* pe     = (const float*)d_in[3];
  const float* w_pos1 = (const float*)d_in[4];
  const float* b_pos1 = (const float*)d_in[5];
  const float* w_pos2 = (const float*)d_in[6];
  const float* b_pos2 = (const float*)d_in[7];
  const float* w1     = (const float*)d_in[8];
  const float* b1     = (const float*)d_in[9];
  const float* w2     = (const float*)d_in[10];
  const float* b2     = (const float*)d_in[11];
  const float* w3     = (const float*)d_in[12];
  const float* b3     = (const float*)d_in[13];
  const float* w4     = (const float*)d_in[14];
  const float* b4     = (const float*)d_in[15];
  const float* ln_g   = (const float*)d_in[16];
  const float* ln_b   = (const float*)d_in[17];

  char* ws = (char*)d_ws;
  bf16* pe_bf  = (bf16*)(ws + 0);
  bf16* wp1_bf = (bf16*)(ws + 524288);
  bf16* wp2_bf = (bf16*)(ws + 819200);
  bf16* w1_bf  = (bf16*)(ws + 3178496);
  bf16* w2_bf  = (bf16*)(ws + 7372800);
  bf16* w3_bf  = (bf16*)(ws + 11567104);
  bf16* w4_bf  = (bf16*)(ws + 15761408);
  bf16* h1     = (bf16*)(ws + 19955712);
  bf16* zn_bf  = (bf16*)(ws + 24674304);
  bf16* x_bf   = (bf16*)(ws + 41451520);
  float* wh    = (float*)(ws + 58228736);
  float* cwhz  = (float*)(ws + 66617344);
  bf16*  x1n   = (bf16*)(ws + 66617344);
  bf16*  g     = (bf16*)(ws + 100171776);
  float* x1    = (float*)(ws + 24674304);
  float* out   = (float*)d_out;

  CvtSegs segs;
  segs.src[0] = pe;  segs.src[1] = w_pos1; segs.src[2] = w_pos2;
  segs.src[3] = w1;  segs.src[4] = w2;     segs.src[5] = w3; segs.src[6] = w4;
  int bo[8] = {0, 256, 400, 1552, 3600, 5648, 7696, 9744};
  for (int i = 0; i < 8; ++i) segs.blk_off[i] = bo[i];
  cvt7_k<<<9744, 256, 0, stream>>>(segs, (bf16*)ws);
  cvt_k<<<8192, 256, 0, stream>>>(x, x_bf, 8388608);

  // 1. zn = LN(z) -> bf16
  ln_k<<<8192, 256, 0, stream>>>(z, zn_bf, ln_g, ln_b);
  // 2. h1 = gelu(pe @ w_pos1^T + b_pos1) -> bf16   [2048, 1152], K=128
  gemm_k<0><<<dim3(9, 16), 256, 0, stream>>>(pe_bf, wp1_bf, b_pos1, h1, nullptr, nullptr, 2048, 1152, 128);
  // 3. wh = window * (h1 @ w_pos2^T + b_pos2) f32  [2048, 1024], K=1152
  //    64-wide tile: 256 blocks = 1/CU (was 128 = 0.5/CU)
  gemm64_k<1><<<dim3(16, 16), 256, 0, stream>>>(h1, wp2_bf, b_pos2, wh, a, nullptr, 2048, 1024, 1152);
  // 4. cwhz = causal depthwise conv(zn, wh) f32    [4, 2048, 1024]
  conv_k<<<dim3(32, 16, 4), 256, 0, stream>>>(zn_bf, wh, a, cwhz);
  // 5. g1 = gelu(x @ w1^T + b1) -> bf16            [8192, 2048], K=1024
  gemm_k<0><<<dim3(16, 64), 256, 0, stream>>>(x_bf, w1_bf, b1, g, nullptr, nullptr, 8192, 2048, 1024);
  // 6. x1 = (g1 @ w2^T + b2) * cwhz + z   f32      [8192, 1024], K=2048
  //    64-wide tile: 1024 blocks = 4 blocks/CU (was 512 = 2/CU)
  gemm64_k<2><<<dim3(16, 64), 256, 0, stream>>>(g, w2_bf, b2, x1, cwhz, z, 8192, 1024, 2048);
  // 7. x1n = LN(x1) -> bf16
  ln_k<<<8192, 256, 0, stream>>>(x1, x1n, ln_g, ln_b);
  // 8. g3 = gelu(x1n @ w3^T + b3) -> bf16          [8192, 2048], K=1024
  gemm_k<0><<<dim3(16, 64), 256, 0, stream>>>(x1n, w3_bf, b3, g, nullptr, nullptr, 8192, 2048, 1024);
  // 9. out = (g3 @ w4^T + b4) + x1  f32            [8192, 1024], K=2048
  gemm64_k<3><<<dim3(16, 64), 256, 0, stream>>>(g, w4_bf, b4, out, x1, nullptr, 8192, 1024, 2048);
}

// Round 7
// 424.512 us; speedup vs baseline: 1.2438x; 1.0465x over previous
//
#include <hip/hip_runtime.h>
#include <hip/hip_bf16.h>
#include <cmath>

typedef __hip_bfloat16 bf16;
typedef __attribute__((ext_vector_type(8))) short bf16x8;
typedef __attribute__((ext_vector_type(4))) float f32x4;

static __device__ __forceinline__ float b2f(bf16 v) { return __bfloat162float(v); }
static __device__ __forceinline__ bf16 f2b(float v) { return __float2bfloat16(v); }
static __device__ __forceinline__ float us2f(unsigned short u) {
  return __uint_as_float(((unsigned)u) << 16);
}

static __device__ __forceinline__ void gl2lds16(const bf16* g, bf16* l) {
  __builtin_amdgcn_global_load_lds(
      (const __attribute__((address_space(1))) void*)g,
      (__attribute__((address_space(3))) void*)l, 16, 0, 0);
}

// tanh-form GELU: |err vs erf-form| <~1e-3, far below bf16 rounding of outputs
static __device__ __forceinline__ float gelu_fast(float v) {
  float u = v * (0.7978845608f + 0.0356774081f * v * v);
  float e = __expf(2.f * u);
  return v * (e * __frcp_rn(e + 1.f));
}

// XCD-aware bijective swizzle (m204)
static __device__ __forceinline__ int xcd_swz(int lid, int nwg) {
  const int q = nwg >> 3, r = nwg & 7;
  const int xcd = lid & 7, loc = lid >> 3;
  const int base = (xcd < r) ? xcd * (q + 1) : r * (q + 1) + (xcd - r) * q;
  return base + loc;
}

// ---------------- fused f32 -> bf16 convert for the 7 weight tensors ----------------
struct CvtSegs { const float* src[7]; int blk_off[8]; };
__global__ __launch_bounds__(256) void cvt7_k(CvtSegs s, bf16* __restrict__ dst0)
{
  int b = blockIdx.x;
  int seg = 0;
#pragma unroll
  for (int i = 0; i < 6; ++i) seg += (b >= s.blk_off[i + 1]) ? 1 : 0;
  const float* src = s.src[seg] + (size_t)(b - s.blk_off[seg]) * 1024;
  bf16* dst = dst0 + (size_t)b * 1024;
  int idx = threadIdx.x * 4;
  float4 v = *(const float4*)(src + idx);
  union { bf16 bb[4]; ushort4 u; } o;
  o.bb[0] = f2b(v.x); o.bb[1] = f2b(v.y); o.bb[2] = f2b(v.z); o.bb[3] = f2b(v.w);
  *(ushort4*)(dst + idx) = o.u;
}

__global__ __launch_bounds__(256) void cvt_k(const float* __restrict__ in,
                                             bf16* __restrict__ out, int n)
{
  int idx = (blockIdx.x * 256 + threadIdx.x) * 4;
  if (idx >= n) return;
  float4 v = *(const float4*)(in + idx);
  union { bf16 b[4]; ushort4 u; } o;
  o.b[0] = f2b(v.x); o.b[1] = f2b(v.y); o.b[2] = f2b(v.z); o.b[3] = f2b(v.w);
  *(ushort4*)(out + idx) = o.u;
}

// ---------------- LayerNorm over rows of 1024: f32 in, bf16 out ----------------
__global__ __launch_bounds__(256) void ln_k(const float* __restrict__ X, bf16* __restrict__ Y,
                                            const float* __restrict__ gamma,
                                            const float* __restrict__ beta)
{
  __shared__ float red[16];
  const int row = blockIdx.x, tid = threadIdx.x;
  float4 v = *(const float4*)(X + (size_t)row * 1024 + tid * 4);
  float s  = v.x + v.y + v.z + v.w;
  float s2 = v.x * v.x + v.y * v.y + v.z * v.z + v.w * v.w;
#pragma unroll
  for (int m = 32; m; m >>= 1) { s += __shfl_xor(s, m, 64); s2 += __shfl_xor(s2, m, 64); }
  const int wid = tid >> 6;
  if ((tid & 63) == 0) { red[wid] = s; red[wid + 8] = s2; }
  __syncthreads();
  s  = red[0] + red[1] + red[2] + red[3];
  s2 = red[8] + red[9] + red[10] + red[11];
  const float mu  = s * (1.f / 1024.f);
  const float var = s2 * (1.f / 1024.f) - mu * mu;
  const float rs  = rsqrtf(var + 1e-5f);
  float4 g = *(const float4*)(gamma + tid * 4);
  float4 bt = *(const float4*)(beta + tid * 4);
  union { bf16 b[4]; ushort4 u; } o;
  o.b[0] = f2b((v.x - mu) * rs * g.x + bt.x);
  o.b[1] = f2b((v.y - mu) * rs * g.y + bt.y);
  o.b[2] = f2b((v.z - mu) * rs * g.z + bt.z);
  o.b[3] = f2b((v.w - mu) * rs * g.w + bt.w);
  *(ushort4*)(Y + (size_t)row * 1024 + tid * 4) = o.u;
}

// ================= GEMM 128x128 BK=32 (4 waves, 3-stage async) — step 2 only =========
template<int EPI>
__global__ __launch_bounds__(256, 3) void gemm_k(
    const bf16* __restrict__ A, const bf16* __restrict__ W,
    const float* __restrict__ bias, void* __restrict__ Out,
    const void* __restrict__ aux0, const void* __restrict__ aux1,
    int M, int N, int K)
{
  __shared__ bf16 As[3][128 * 32];
  __shared__ bf16 Bs[3][128 * 32];
  const int tid = threadIdx.x;
  const int wid = tid >> 6, lane = tid & 63;
  const int quad = lane >> 4, l16 = lane & 15;
  const int wm = wid >> 1, wn = wid & 1;

  const int nwg = gridDim.x * gridDim.y;
  int lid = xcd_swz(blockIdx.y * gridDim.x + blockIdx.x, nwg);
  const int bx = lid % gridDim.x, by = lid / gridDim.x;
  const int m0 = by * 128, n0 = bx * 128;

  f32x4 acc[4][4];
#pragma unroll
  for (int i = 0; i < 4; ++i)
#pragma unroll
    for (int j = 0; j < 4; ++j) acc[i][j] = (f32x4){0.f, 0.f, 0.f, 0.f};

  const bf16 *ga[2], *gb[2];
  int ldso[2];
#pragma unroll
  for (int r = 0; r < 2; ++r) {
    int p = r * 256 + wid * 64 + lane;
    int row = p >> 2;
    int sko = ((p & 3) ^ ((p >> 3) & 3)) << 3;
    ga[r] = A + (size_t)(m0 + row) * K + sko;
    gb[r] = W + (size_t)(n0 + row) * K + sko;
    ldso[r] = (r * 256 + wid * 64) * 8;
  }
  int apos[4], bpos[4];
#pragma unroll
  for (int i = 0; i < 4; ++i) {
    int ar = wm * 64 + i * 16 + l16;
    apos[i] = (ar * 4 + (quad ^ ((ar >> 1) & 3))) * 8;
    int br = wn * 64 + i * 16 + l16;
    bpos[i] = (br * 4 + (quad ^ ((br >> 1) & 3))) * 8;
  }

  const int niter = K >> 5;
#pragma unroll
  for (int t = 0; t < 2; ++t)
#pragma unroll
    for (int r = 0; r < 2; ++r) {
      gl2lds16(ga[r] + t * 32, &As[t][ldso[r]]);
      gl2lds16(gb[r] + t * 32, &Bs[t][ldso[r]]);
    }

  int cur = 0;
  for (int k = 0; k < niter; ++k) {
    if (k == niter - 1) { asm volatile("s_waitcnt vmcnt(0)" ::: "memory"); }
    else               { asm volatile("s_waitcnt vmcnt(4)" ::: "memory"); }
    asm volatile("s_barrier" ::: "memory");

    const bf16* as = As[cur];
    const bf16* bs = Bs[cur];
    bf16x8 af[4], bfr[4];
#pragma unroll
    for (int i = 0; i < 4; ++i) af[i]  = *(const bf16x8*)(as + apos[i]);
#pragma unroll
    for (int j = 0; j < 4; ++j) bfr[j] = *(const bf16x8*)(bs + bpos[j]);
    asm volatile("s_waitcnt lgkmcnt(0)" ::: "memory");

    if (k + 2 < niter) {
      int nb = cur + 2; if (nb >= 3) nb -= 3;
#pragma unroll
      for (int r = 0; r < 2; ++r) {
        gl2lds16(ga[r] + (k + 2) * 32, &As[nb][ldso[r]]);
        gl2lds16(gb[r] + (k + 2) * 32, &Bs[nb][ldso[r]]);
      }
    }
#pragma unroll
    for (int i = 0; i < 4; ++i)
#pragma unroll
      for (int j = 0; j < 4; ++j)
        acc[i][j] = __builtin_amdgcn_mfma_f32_16x16x32_bf16(af[i], bfr[j], acc[i][j], 0, 0, 0);
    cur += 1; if (cur == 3) cur = 0;
  }

  float expa = 0.f;
  if (EPI == 1) expa = expf(((const float*)aux0)[0]);
#pragma unroll
  for (int i = 0; i < 4; ++i) {
    const int gm_base = m0 + wm * 64 + i * 16 + quad * 4;
#pragma unroll
    for (int j = 0; j < 4; ++j) {
      const int gn = n0 + wn * 64 + j * 16 + l16;
      const float bv = bias[gn];
#pragma unroll
      for (int r = 0; r < 4; ++r) {
        const int gm = gm_base + r;
        const size_t off = (size_t)gm * N + gn;
        float v = acc[i][j][r] + bv;
        if (EPI == 0) ((bf16*)Out)[off] = f2b(gelu_fast(v));
        else if (EPI == 1) ((float*)Out)[off] = v * expf(-(float)gm * expa);
        else if (EPI == 2) ((float*)Out)[off] = v * ((const float*)aux0)[off] + ((const float*)aux1)[off];
        else ((float*)Out)[off] = v + ((const float*)aux0)[off];
      }
    }
  }
}

// ========== GEMM 128x128 BK=64 (4 waves, 2-slot, stage-early, 1 barrier/step) ==========
// Halves the per-output step count vs gemm_k (F amortized 2x); 64KB LDS -> 2 blocks/CU
// (the measured saturation point). stage(k+1) issued right after iter k's barrier ->
// vmcnt(0) at iter k+1 has a full step of flight (drain ~free). 8-chunk XOR swizzle:
// chunk' = chunk ^ (row&7); inverse-swizzled global source, swizzled ds_read (rule 21);
// ds_read_b128 = 2 lanes/bank (free); gl2lds dest linear. Fragment data identical to
// two consecutive proven gemm_k K-steps.
template<int EPI>
__global__ __launch_bounds__(256, 2) void gemmw_k(
    const bf16* __restrict__ A, const bf16* __restrict__ W,
    const float* __restrict__ bias, void* __restrict__ Out,
    const void* __restrict__ aux0, const void* __restrict__ aux1,
    int M, int N, int K)
{
  __shared__ bf16 As[2][128 * 64];
  __shared__ bf16 Bs[2][128 * 64];
  const int tid = threadIdx.x;
  const int wid = tid >> 6, lane = tid & 63;
  const int quad = lane >> 4, l16 = lane & 15;
  const int wm = wid >> 1, wn = wid & 1;

  const int nwg = gridDim.x * gridDim.y;
  int lid = xcd_swz(blockIdx.y * gridDim.x + blockIdx.x, nwg);
  const int bx = lid % gridDim.x, by = lid / gridDim.x;
  const int m0 = by * 128, n0 = bx * 128;

  f32x4 acc[4][4];
#pragma unroll
  for (int i = 0; i < 4; ++i)
#pragma unroll
    for (int j = 0; j < 4; ++j) acc[i][j] = (f32x4){0.f, 0.f, 0.f, 0.f};

  // staging: 4 loads/tensor/step; p in 0..1023 -> row=p>>3, chunk-slot=p&7,
  // global chunk c = (p&7) ^ (row&7) (involution). LDS dest linear in p.
  const bf16 *ga[4], *gb[4];
  int ldso[4];
#pragma unroll
  for (int r = 0; r < 4; ++r) {
    int p = r * 256 + tid;
    int row = p >> 3;
    int c = (p & 7) ^ (row & 7);
    ga[r] = A + (size_t)(m0 + row) * K + c * 8;
    gb[r] = W + (size_t)(n0 + row) * K + c * 8;
    ldso[r] = p * 8;
  }
  // fragment reads: row ar, k-chunk (quad + 4*ks), stored at chunk' = chunk ^ (ar&7)
  int apos[4][2], bpos[4][2];
#pragma unroll
  for (int i = 0; i < 4; ++i) {
    int ar = wm * 64 + i * 16 + l16;
    int br = wn * 64 + i * 16 + l16;
#pragma unroll
    for (int ks = 0; ks < 2; ++ks) {
      apos[i][ks] = ar * 64 + (((quad + 4 * ks) ^ (ar & 7)) * 8);
      bpos[i][ks] = br * 64 + (((quad + 4 * ks) ^ (br & 7)) * 8);
    }
  }

  const int niter = K >> 6;

  // prologue: stage tile 0 -> slot 0
#pragma unroll
  for (int r = 0; r < 4; ++r) {
    gl2lds16(ga[r], &As[0][ldso[r]]);
    gl2lds16(gb[r], &Bs[0][ldso[r]]);
  }

  for (int k = 0; k < niter; ++k) {
    asm volatile("s_waitcnt vmcnt(0)" ::: "memory");   // stage(k) landed (full step of flight)
    asm volatile("s_barrier" ::: "memory");            // all writes visible; iter k-1 reads done
    const int cur = k & 1;
    if (k + 1 < niter) {
      const int nxt = cur ^ 1;
#pragma unroll
      for (int r = 0; r < 4; ++r) {
        gl2lds16(ga[r] + (k + 1) * 64, &As[nxt][ldso[r]]);
        gl2lds16(gb[r] + (k + 1) * 64, &Bs[nxt][ldso[r]]);
      }
    }
    const bf16* as = As[cur];
    const bf16* bs = Bs[cur];
    bf16x8 af[4][2], bfr[4][2];
#pragma unroll
    for (int i = 0; i < 4; ++i)
#pragma unroll
      for (int ks = 0; ks < 2; ++ks) af[i][ks] = *(const bf16x8*)(as + apos[i][ks]);
#pragma unroll
    for (int j = 0; j < 4; ++j)
#pragma unroll
      for (int ks = 0; ks < 2; ++ks) bfr[j][ks] = *(const bf16x8*)(bs + bpos[j][ks]);
    asm volatile("s_waitcnt lgkmcnt(0)" ::: "memory");

#pragma unroll
    for (int ks = 0; ks < 2; ++ks)
#pragma unroll
      for (int i = 0; i < 4; ++i)
#pragma unroll
        for (int j = 0; j < 4; ++j)
          acc[i][j] = __builtin_amdgcn_mfma_f32_16x16x32_bf16(af[i][ks], bfr[j][ks], acc[i][j], 0, 0, 0);
  }

  float expa = 0.f;
  if (EPI == 1) expa = expf(((const float*)aux0)[0]);
#pragma unroll
  for (int i = 0; i < 4; ++i) {
    const int gm_base = m0 + wm * 64 + i * 16 + quad * 4;
#pragma unroll
    for (int j = 0; j < 4; ++j) {
      const int gn = n0 + wn * 64 + j * 16 + l16;
      const float bv = bias[gn];
#pragma unroll
      for (int r = 0; r < 4; ++r) {
        const int gm = gm_base + r;
        const size_t off = (size_t)gm * N + gn;
        float v = acc[i][j][r] + bv;
        if (EPI == 0) ((bf16*)Out)[off] = f2b(gelu_fast(v));
        else if (EPI == 1) ((float*)Out)[off] = v * expf(-(float)gm * expa);
        else if (EPI == 2) ((float*)Out)[off] = v * ((const float*)aux0)[off] + ((const float*)aux1)[off];
        else ((float*)Out)[off] = v + ((const float*)aux0)[off];
      }
    }
  }
}

// ---------------- causal depthwise conv ----------------
__global__ __launch_bounds__(256) void conv_k(
    const bf16* __restrict__ zn,    // [B, L, D] bf16
    const float* __restrict__ wh,   // [L, D] f32
    const float* __restrict__ a,
    float* __restrict__ out)        // [B, L, D] f32
{
  __shared__ float whs[64 * 64];
  __shared__ float znt[128 * 64];   // row r holds u = t0 - sb - 64 + r
  const int tid = threadIdx.x;
  const int dd = tid & 63, ttg = tid >> 6;
  const int t0 = blockIdx.x * 64, d0 = blockIdx.y * 64, b = blockIdx.z;
  const float expa = expf(a[0]);
  const float smax = 20.7f / expa;
  const unsigned short* znu = (const unsigned short*)zn;

  float acc[16];
#pragma unroll
  for (int q = 0; q < 16; ++q) acc[q] = 0.f;

  for (int sb = 0; sb <= t0 + 63; sb += 64) {
    if ((float)sb > smax) break;
    float4 wv4[4];
#pragma unroll
    for (int i = 0; i < 4; ++i) {
      int cc = tid + 256 * i;
      int row = cc >> 4, dq = (cc & 15) * 4;
      wv4[i] = *(const float4*)&wh[(size_t)(sb + row) * 1024 + d0 + dq];
    }
    ushort4 zv4[8];
#pragma unroll
    for (int i = 0; i < 8; ++i) {
      int cc = tid + 256 * i;
      int row = cc >> 4, dq = (cc & 15) * 4;
      int u = t0 - sb - 64 + row;
      zv4[i] = (u >= 0) ? *(const ushort4*)&znu[((size_t)b * 2048 + u) * 1024 + d0 + dq]
                        : make_ushort4(0, 0, 0, 0);
    }
#pragma unroll
    for (int i = 0; i < 4; ++i) {
      int cc = tid + 256 * i;
      *(float4*)&whs[(cc >> 4) * 64 + (cc & 15) * 4] = wv4[i];
    }
#pragma unroll
    for (int i = 0; i < 8; ++i) {
      int cc = tid + 256 * i;
      float4 o;
      o.x = us2f(zv4[i].x); o.y = us2f(zv4[i].y); o.z = us2f(zv4[i].z); o.w = us2f(zv4[i].w);
      *(float4*)&znt[(cc >> 4) * 64 + (cc & 15) * 4] = o;
    }
    __syncthreads();

    float win[16];
#pragma unroll
    for (int q = 0; q < 16; ++q) win[q] = znt[(ttg * 16 + q + 64) * 64 + dd];
#pragma unroll
    for (int ss = 0; ss < 64; ++ss) {
      float wv = whs[ss * 64 + dd];
#pragma unroll
      for (int q = 0; q < 16; ++q) acc[q] += wv * win[q];
      if (ss < 63) {
#pragma unroll
        for (int q = 15; q >= 1; --q) win[q] = win[q - 1];
        win[0] = znt[(ttg * 16 + 63 - ss) * 64 + dd];
      }
    }
    __syncthreads();
  }
#pragma unroll
  for (int q = 0; q < 16; ++q) {
    int t = t0 + ttg * 16 + q;
    out[((size_t)b * 2048 + t) * 1024 + d0 + dd] = acc[q];
  }
}

extern "C" void kernel_launch(void* const* d_in, const int* in_sizes, int n_in,
                              void* d_out, int out_size, void* d_ws, size_t ws_size,
                              hipStream_t stream)
{
  const float* z      = (const float*)d_in[0];
  const float* x      = (const float*)d_in[1];
  const float* a      = (const float*)d_in[2];
  const float* pe     = (const float*)d_in[3];
  const float* w_pos1 = (const float*)d_in[4];
  const float* b_pos1 = (const float*)d_in[5];
  const float* w_pos2 = (const float*)d_in[6];
  const float* b_pos2 = (const float*)d_in[7];
  const float* w1     = (const float*)d_in[8];
  const float* b1     = (const float*)d_in[9];
  const float* w2     = (const float*)d_in[10];
  const float* b2     = (const float*)d_in[11];
  const float* w3     = (const float*)d_in[12];
  const float* b3     = (const float*)d_in[13];
  const float* w4     = (const float*)d_in[14];
  const float* b4     = (const float*)d_in[15];
  const float* ln_g   = (const float*)d_in[16];
  const float* ln_b   = (const float*)d_in[17];

  char* ws = (char*)d_ws;
  bf16* pe_bf  = (bf16*)(ws + 0);
  bf16* wp1_bf = (bf16*)(ws + 524288);
  bf16* wp2_bf = (bf16*)(ws + 819200);
  bf16* w1_bf  = (bf16*)(ws + 3178496);
  bf16* w2_bf  = (bf16*)(ws + 7372800);
  bf16* w3_bf  = (bf16*)(ws + 11567104);
  bf16* w4_bf  = (bf16*)(ws + 15761408);
  bf16* h1     = (bf16*)(ws + 19955712);
  bf16* zn_bf  = (bf16*)(ws + 24674304);
  bf16* x_bf   = (bf16*)(ws + 41451520);
  float* wh    = (float*)(ws + 58228736);
  float* cwhz  = (float*)(ws + 66617344);
  bf16*  x1n   = (bf16*)(ws + 66617344);
  bf16*  g     = (bf16*)(ws + 100171776);
  float* x1    = (float*)(ws + 24674304);
  float* out   = (float*)d_out;

  CvtSegs segs;
  segs.src[0] = pe;  segs.src[1] = w_pos1; segs.src[2] = w_pos2;
  segs.src[3] = w1;  segs.src[4] = w2;     segs.src[5] = w3; segs.src[6] = w4;
  int bo[8] = {0, 256, 400, 1552, 3600, 5648, 7696, 9744};
  for (int i = 0; i < 8; ++i) segs.blk_off[i] = bo[i];
  cvt7_k<<<9744, 256, 0, stream>>>(segs, (bf16*)ws);
  cvt_k<<<8192, 256, 0, stream>>>(x, x_bf, 8388608);

  // 1. zn = LN(z) -> bf16
  ln_k<<<8192, 256, 0, stream>>>(z, zn_bf, ln_g, ln_b);
  // 2. h1 = gelu(pe @ w_pos1^T + b_pos1) -> bf16   [2048, 1152], K=128
  gemm_k<0><<<dim3(9, 16), 256, 0, stream>>>(pe_bf, wp1_bf, b_pos1, h1, nullptr, nullptr, 2048, 1152, 128);
  // 3. wh = window * (h1 @ w_pos2^T + b_pos2) f32  [2048, 1024], K=1152 (niter=18)
  gemmw_k<1><<<dim3(8, 16), 256, 0, stream>>>(h1, wp2_bf, b_pos2, wh, a, nullptr, 2048, 1024, 1152);
  // 4. cwhz = causal depthwise conv(zn, wh) f32    [4, 2048, 1024]
  conv_k<<<dim3(32, 16, 4), 256, 0, stream>>>(zn_bf, wh, a, cwhz);
  // 5. g1 = gelu(x @ w1^T + b1) -> bf16            [8192, 2048], K=1024 (niter=16)
  gemmw_k<0><<<dim3(16, 64), 256, 0, stream>>>(x_bf, w1_bf, b1, g, nullptr, nullptr, 8192, 2048, 1024);
  // 6. x1 = (g1 @ w2^T + b2) * cwhz + z   f32      [8192, 1024], K=2048 (niter=32)
  gemmw_k<2><<<dim3(8, 64), 256, 0, stream>>>(g, w2_bf, b2, x1, cwhz, z, 8192, 1024, 2048);
  // 7. x1n = LN(x1) -> bf16
  ln_k<<<8192, 256, 0, stream>>>(x1, x1n, ln_g, ln_b);
  // 8. g3 = gelu(x1n @ w3^T + b3) -> bf16          [8192, 2048], K=1024
  gemmw_k<0><<<dim3(16, 64), 256, 0, stream>>>(x1n, w3_bf, b3, g, nullptr, nullptr, 8192, 2048, 1024);
  // 9. out = (g3 @ w4^T + b4) + x1  f32            [8192, 1024], K=2048
  gemmw_k<3><<<dim3(8, 64), 256, 0, stream>>>(g, w4_bf, b4, out, x1, nullptr, 8192, 1024, 2048);
}

// Round 8
// 422.585 us; speedup vs baseline: 1.2494x; 1.0046x over previous
//
#include <hip/hip_runtime.h>
#include <hip/hip_bf16.h>
#include <cmath>

typedef __hip_bfloat16 bf16;
typedef __attribute__((ext_vector_type(8))) short bf16x8;
typedef __attribute__((ext_vector_type(4))) float f32x4;

static __device__ __forceinline__ float b2f(bf16 v) { return __bfloat162float(v); }
static __device__ __forceinline__ bf16 f2b(float v) { return __float2bfloat16(v); }
static __device__ __forceinline__ float us2f(unsigned short u) {
  return __uint_as_float(((unsigned)u) << 16);
}

static __device__ __forceinline__ void gl2lds16(const bf16* g, bf16* l) {
  __builtin_amdgcn_global_load_lds(
      (const __attribute__((address_space(1))) void*)g,
      (__attribute__((address_space(3))) void*)l, 16, 0, 0);
}

// tanh-form GELU: |err vs erf-form| <~1e-3, far below bf16 rounding of outputs
static __device__ __forceinline__ float gelu_fast(float v) {
  float u = v * (0.7978845608f + 0.0356774081f * v * v);
  float e = __expf(2.f * u);
  return v * (e * __frcp_rn(e + 1.f));
}

// XCD-aware bijective swizzle (m204)
static __device__ __forceinline__ int xcd_swz(int lid, int nwg) {
  const int q = nwg >> 3, r = nwg & 7;
  const int xcd = lid & 7, loc = lid >> 3;
  const int base = (xcd < r) ? xcd * (q + 1) : r * (q + 1) + (xcd - r) * q;
  return base + loc;
}

// ---------------- fused f32 -> bf16 convert for the 7 weight tensors ----------------
struct CvtSegs { const float* src[7]; int blk_off[8]; };
__global__ __launch_bounds__(256) void cvt7_k(CvtSegs s, bf16* __restrict__ dst0)
{
  int b = blockIdx.x;
  int seg = 0;
#pragma unroll
  for (int i = 0; i < 6; ++i) seg += (b >= s.blk_off[i + 1]) ? 1 : 0;
  const float* src = s.src[seg] + (size_t)(b - s.blk_off[seg]) * 1024;
  bf16* dst = dst0 + (size_t)b * 1024;
  int idx = threadIdx.x * 4;
  float4 v = *(const float4*)(src + idx);
  union { bf16 bb[4]; ushort4 u; } o;
  o.bb[0] = f2b(v.x); o.bb[1] = f2b(v.y); o.bb[2] = f2b(v.z); o.bb[3] = f2b(v.w);
  *(ushort4*)(dst + idx) = o.u;
}

__global__ __launch_bounds__(256) void cvt_k(const float* __restrict__ in,
                                             bf16* __restrict__ out, int n)
{
  int idx = (blockIdx.x * 256 + threadIdx.x) * 4;
  if (idx >= n) return;
  float4 v = *(const float4*)(in + idx);
  union { bf16 b[4]; ushort4 u; } o;
  o.b[0] = f2b(v.x); o.b[1] = f2b(v.y); o.b[2] = f2b(v.z); o.b[3] = f2b(v.w);
  *(ushort4*)(out + idx) = o.u;
}

// ---------------- LayerNorm over rows of 1024: f32 in, bf16 out ----------------
__global__ __launch_bounds__(256) void ln_k(const float* __restrict__ X, bf16* __restrict__ Y,
                                            const float* __restrict__ gamma,
                                            const float* __restrict__ beta)
{
  __shared__ float red[16];
  const int row = blockIdx.x, tid = threadIdx.x;
  float4 v = *(const float4*)(X + (size_t)row * 1024 + tid * 4);
  float s  = v.x + v.y + v.z + v.w;
  float s2 = v.x * v.x + v.y * v.y + v.z * v.z + v.w * v.w;
#pragma unroll
  for (int m = 32; m; m >>= 1) { s += __shfl_xor(s, m, 64); s2 += __shfl_xor(s2, m, 64); }
  const int wid = tid >> 6;
  if ((tid & 63) == 0) { red[wid] = s; red[wid + 8] = s2; }
  __syncthreads();
  s  = red[0] + red[1] + red[2] + red[3];
  s2 = red[8] + red[9] + red[10] + red[11];
  const float mu  = s * (1.f / 1024.f);
  const float var = s2 * (1.f / 1024.f) - mu * mu;
  const float rs  = rsqrtf(var + 1e-5f);
  float4 g = *(const float4*)(gamma + tid * 4);
  float4 bt = *(const float4*)(beta + tid * 4);
  union { bf16 b[4]; ushort4 u; } o;
  o.b[0] = f2b((v.x - mu) * rs * g.x + bt.x);
  o.b[1] = f2b((v.y - mu) * rs * g.y + bt.y);
  o.b[2] = f2b((v.z - mu) * rs * g.z + bt.z);
  o.b[3] = f2b((v.w - mu) * rs * g.w + bt.w);
  *(ushort4*)(Y + (size_t)row * 1024 + tid * 4) = o.u;
}

// ================= GEMM 128x128 BK=32 (4 waves, 3-stage async) =================
// QCLIP>0: skip blocks whose m0 > smax + QCLIP (window weight < 1e-9 -> rows never
// read downstream; a[] passed via aux1). Wave-uniform return before any loads/barriers.
template<int EPI, int QCLIP = 0>
__global__ __launch_bounds__(256, 3) void gemm_k(
    const bf16* __restrict__ A, const bf16* __restrict__ W,
    const float* __restrict__ bias, void* __restrict__ Out,
    const void* __restrict__ aux0, const void* __restrict__ aux1,
    int M, int N, int K)
{
  __shared__ bf16 As[3][128 * 32];
  __shared__ bf16 Bs[3][128 * 32];
  const int tid = threadIdx.x;
  const int wid = tid >> 6, lane = tid & 63;
  const int quad = lane >> 4, l16 = lane & 15;
  const int wm = wid >> 1, wn = wid & 1;

  const int nwg = gridDim.x * gridDim.y;
  int lid = xcd_swz(blockIdx.y * gridDim.x + blockIdx.x, nwg);
  const int bx = lid % gridDim.x, by = lid / gridDim.x;
  const int m0 = by * 128, n0 = bx * 128;

  if (QCLIP > 0) {
    const float smax = 20.7f / __expf(((const float*)aux1)[0]);
    if ((float)(m0 - QCLIP) > smax) return;
  }

  f32x4 acc[4][4];
#pragma unroll
  for (int i = 0; i < 4; ++i)
#pragma unroll
    for (int j = 0; j < 4; ++j) acc[i][j] = (f32x4){0.f, 0.f, 0.f, 0.f};

  const bf16 *ga[2], *gb[2];
  int ldso[2];
#pragma unroll
  for (int r = 0; r < 2; ++r) {
    int p = r * 256 + wid * 64 + lane;
    int row = p >> 2;
    int sko = ((p & 3) ^ ((p >> 3) & 3)) << 3;
    ga[r] = A + (size_t)(m0 + row) * K + sko;
    gb[r] = W + (size_t)(n0 + row) * K + sko;
    ldso[r] = (r * 256 + wid * 64) * 8;
  }
  int apos[4], bpos[4];
#pragma unroll
  for (int i = 0; i < 4; ++i) {
    int ar = wm * 64 + i * 16 + l16;
    apos[i] = (ar * 4 + (quad ^ ((ar >> 1) & 3))) * 8;
    int br = wn * 64 + i * 16 + l16;
    bpos[i] = (br * 4 + (quad ^ ((br >> 1) & 3))) * 8;
  }

  const int niter = K >> 5;
#pragma unroll
  for (int t = 0; t < 2; ++t)
#pragma unroll
    for (int r = 0; r < 2; ++r) {
      gl2lds16(ga[r] + t * 32, &As[t][ldso[r]]);
      gl2lds16(gb[r] + t * 32, &Bs[t][ldso[r]]);
    }

  int cur = 0;
  for (int k = 0; k < niter; ++k) {
    if (k == niter - 1) { asm volatile("s_waitcnt vmcnt(0)" ::: "memory"); }
    else               { asm volatile("s_waitcnt vmcnt(4)" ::: "memory"); }
    asm volatile("s_barrier" ::: "memory");

    const bf16* as = As[cur];
    const bf16* bs = Bs[cur];
    bf16x8 af[4], bfr[4];
#pragma unroll
    for (int i = 0; i < 4; ++i) af[i]  = *(const bf16x8*)(as + apos[i]);
#pragma unroll
    for (int j = 0; j < 4; ++j) bfr[j] = *(const bf16x8*)(bs + bpos[j]);
    asm volatile("s_waitcnt lgkmcnt(0)" ::: "memory");

    if (k + 2 < niter) {
      int nb = cur + 2; if (nb >= 3) nb -= 3;
#pragma unroll
      for (int r = 0; r < 2; ++r) {
        gl2lds16(ga[r] + (k + 2) * 32, &As[nb][ldso[r]]);
        gl2lds16(gb[r] + (k + 2) * 32, &Bs[nb][ldso[r]]);
      }
    }
#pragma unroll
    for (int i = 0; i < 4; ++i)
#pragma unroll
      for (int j = 0; j < 4; ++j)
        acc[i][j] = __builtin_amdgcn_mfma_f32_16x16x32_bf16(af[i], bfr[j], acc[i][j], 0, 0, 0);
    cur += 1; if (cur == 3) cur = 0;
  }

  float expa = 0.f;
  if (EPI == 1) expa = expf(((const float*)aux0)[0]);
#pragma unroll
  for (int i = 0; i < 4; ++i) {
    const int gm_base = m0 + wm * 64 + i * 16 + quad * 4;
#pragma unroll
    for (int j = 0; j < 4; ++j) {
      const int gn = n0 + wn * 64 + j * 16 + l16;
      const float bv = bias[gn];
#pragma unroll
      for (int r = 0; r < 4; ++r) {
        const int gm = gm_base + r;
        const size_t off = (size_t)gm * N + gn;
        float v = acc[i][j][r] + bv;
        if (EPI == 0) ((bf16*)Out)[off] = f2b(gelu_fast(v));
        else if (EPI == 1) ((float*)Out)[off] = v * expf(-(float)gm * expa);
        else if (EPI == 2) ((float*)Out)[off] = v * ((const float*)aux0)[off] + ((const float*)aux1)[off];
        else ((float*)Out)[off] = v + ((const float*)aux0)[off];
      }
    }
  }
}

// ========== GEMM 128x128 BK=64 (4 waves, 2-slot, stage-early) — steps 3,6,9 ==========
// QCLIP>0: same row-truncation skip as gemm_k (a[] via aux0 here; step 3's wh rows
// beyond smax+63 are never read by conv_k).
template<int EPI, int QCLIP = 0>
__global__ __launch_bounds__(256, 2) void gemmw_k(
    const bf16* __restrict__ A, const bf16* __restrict__ W,
    const float* __restrict__ bias, void* __restrict__ Out,
    const void* __restrict__ aux0, const void* __restrict__ aux1,
    int M, int N, int K)
{
  __shared__ bf16 As[2][128 * 64];
  __shared__ bf16 Bs[2][128 * 64];
  const int tid = threadIdx.x;
  const int wid = tid >> 6, lane = tid & 63;
  const int quad = lane >> 4, l16 = lane & 15;
  const int wm = wid >> 1, wn = wid & 1;

  const int nwg = gridDim.x * gridDim.y;
  int lid = xcd_swz(blockIdx.y * gridDim.x + blockIdx.x, nwg);
  const int bx = lid % gridDim.x, by = lid / gridDim.x;
  const int m0 = by * 128, n0 = bx * 128;

  if (QCLIP > 0) {
    const float smax = 20.7f / __expf(((const float*)aux0)[0]);
    if ((float)(m0 - QCLIP) > smax) return;
  }

  f32x4 acc[4][4];
#pragma unroll
  for (int i = 0; i < 4; ++i)
#pragma unroll
    for (int j = 0; j < 4; ++j) acc[i][j] = (f32x4){0.f, 0.f, 0.f, 0.f};

  // staging: 4 loads/tensor/step; p in 0..1023 -> row=p>>3, chunk-slot=p&7,
  // global chunk c = (p&7) ^ (row&7) (involution). LDS dest linear in p.
  const bf16 *ga[4], *gb[4];
  int ldso[4];
#pragma unroll
  for (int r = 0; r < 4; ++r) {
    int p = r * 256 + tid;
    int row = p >> 3;
    int c = (p & 7) ^ (row & 7);
    ga[r] = A + (size_t)(m0 + row) * K + c * 8;
    gb[r] = W + (size_t)(n0 + row) * K + c * 8;
    ldso[r] = p * 8;
  }
  int apos[4][2], bpos[4][2];
#pragma unroll
  for (int i = 0; i < 4; ++i) {
    int ar = wm * 64 + i * 16 + l16;
    int br = wn * 64 + i * 16 + l16;
#pragma unroll
    for (int ks = 0; ks < 2; ++ks) {
      apos[i][ks] = ar * 64 + (((quad + 4 * ks) ^ (ar & 7)) * 8);
      bpos[i][ks] = br * 64 + (((quad + 4 * ks) ^ (br & 7)) * 8);
    }
  }

  const int niter = K >> 6;

#pragma unroll
  for (int r = 0; r < 4; ++r) {
    gl2lds16(ga[r], &As[0][ldso[r]]);
    gl2lds16(gb[r], &Bs[0][ldso[r]]);
  }

  for (int k = 0; k < niter; ++k) {
    asm volatile("s_waitcnt vmcnt(0)" ::: "memory");
    asm volatile("s_barrier" ::: "memory");
    const int cur = k & 1;
    if (k + 1 < niter) {
      const int nxt = cur ^ 1;
#pragma unroll
      for (int r = 0; r < 4; ++r) {
        gl2lds16(ga[r] + (k + 1) * 64, &As[nxt][ldso[r]]);
        gl2lds16(gb[r] + (k + 1) * 64, &Bs[nxt][ldso[r]]);
      }
    }
    const bf16* as = As[cur];
    const bf16* bs = Bs[cur];
    bf16x8 af[4][2], bfr[4][2];
#pragma unroll
    for (int i = 0; i < 4; ++i)
#pragma unroll
      for (int ks = 0; ks < 2; ++ks) af[i][ks] = *(const bf16x8*)(as + apos[i][ks]);
#pragma unroll
    for (int j = 0; j < 4; ++j)
#pragma unroll
      for (int ks = 0; ks < 2; ++ks) bfr[j][ks] = *(const bf16x8*)(bs + bpos[j][ks]);
    asm volatile("s_waitcnt lgkmcnt(0)" ::: "memory");

#pragma unroll
    for (int ks = 0; ks < 2; ++ks)
#pragma unroll
      for (int i = 0; i < 4; ++i)
#pragma unroll
        for (int j = 0; j < 4; ++j)
          acc[i][j] = __builtin_amdgcn_mfma_f32_16x16x32_bf16(af[i][ks], bfr[j][ks], acc[i][j], 0, 0, 0);
  }

  float expa = 0.f;
  if (EPI == 1) expa = expf(((const float*)aux0)[0]);
#pragma unroll
  for (int i = 0; i < 4; ++i) {
    const int gm_base = m0 + wm * 64 + i * 16 + quad * 4;
#pragma unroll
    for (int j = 0; j < 4; ++j) {
      const int gn = n0 + wn * 64 + j * 16 + l16;
      const float bv = bias[gn];
#pragma unroll
      for (int r = 0; r < 4; ++r) {
        const int gm = gm_base + r;
        const size_t off = (size_t)gm * N + gn;
        float v = acc[i][j][r] + bv;
        if (EPI == 0) ((bf16*)Out)[off] = f2b(gelu_fast(v));
        else if (EPI == 1) ((float*)Out)[off] = v * expf(-(float)gm * expa);
        else if (EPI == 2) ((float*)Out)[off] = v * ((const float*)aux0)[off] + ((const float*)aux1)[off];
        else ((float*)Out)[off] = v + ((const float*)aux0)[off];
      }
    }
  }
}

// ---------------- causal depthwise conv ----------------
__global__ __launch_bounds__(256) void conv_k(
    const bf16* __restrict__ zn,    // [B, L, D] bf16
    const float* __restrict__ wh,   // [L, D] f32
    const float* __restrict__ a,
    float* __restrict__ out)        // [B, L, D] f32
{
  __shared__ float whs[64 * 64];
  __shared__ float znt[128 * 64];   // row r holds u = t0 - sb - 64 + r
  const int tid = threadIdx.x;
  const int dd = tid & 63, ttg = tid >> 6;
  const int t0 = blockIdx.x * 64, d0 = blockIdx.y * 64, b = blockIdx.z;
  const float expa = expf(a[0]);
  const float smax = 20.7f / expa;
  const unsigned short* znu = (const unsigned short*)zn;

  float acc[16];
#pragma unroll
  for (int q = 0; q < 16; ++q) acc[q] = 0.f;

  for (int sb = 0; sb <= t0 + 63; sb += 64) {
    if ((float)sb > smax) break;
    float4 wv4[4];
#pragma unroll
    for (int i = 0; i < 4; ++i) {
      int cc = tid + 256 * i;
      int row = cc >> 4, dq = (cc & 15) * 4;
      wv4[i] = *(const float4*)&wh[(size_t)(sb + row) * 1024 + d0 + dq];
    }
    ushort4 zv4[8];
#pragma unroll
    for (int i = 0; i < 8; ++i) {
      int cc = tid + 256 * i;
      int row = cc >> 4, dq = (cc & 15) * 4;
      int u = t0 - sb - 64 + row;
      zv4[i] = (u >= 0) ? *(const ushort4*)&znu[((size_t)b * 2048 + u) * 1024 + d0 + dq]
                        : make_ushort4(0, 0, 0, 0);
    }
#pragma unroll
    for (int i = 0; i < 4; ++i) {
      int cc = tid + 256 * i;
      *(float4*)&whs[(cc >> 4) * 64 + (cc & 15) * 4] = wv4[i];
    }
#pragma unroll
    for (int i = 0; i < 8; ++i) {
      int cc = tid + 256 * i;
      float4 o;
      o.x = us2f(zv4[i].x); o.y = us2f(zv4[i].y); o.z = us2f(zv4[i].z); o.w = us2f(zv4[i].w);
      *(float4*)&znt[(cc >> 4) * 64 + (cc & 15) * 4] = o;
    }
    __syncthreads();

    float win[16];
#pragma unroll
    for (int q = 0; q < 16; ++q) win[q] = znt[(ttg * 16 + q + 64) * 64 + dd];
#pragma unroll
    for (int ss = 0; ss < 64; ++ss) {
      float wv = whs[ss * 64 + dd];
#pragma unroll
      for (int q = 0; q < 16; ++q) acc[q] += wv * win[q];
      if (ss < 63) {
#pragma unroll
        for (int q = 15; q >= 1; --q) win[q] = win[q - 1];
        win[0] = znt[(ttg * 16 + 63 - ss) * 64 + dd];
      }
    }
    __syncthreads();
  }
#pragma unroll
  for (int q = 0; q < 16; ++q) {
    int t = t0 + ttg * 16 + q;
    out[((size_t)b * 2048 + t) * 1024 + d0 + dd] = acc[q];
  }
}

extern "C" void kernel_launch(void* const* d_in, const int* in_sizes, int n_in,
                              void* d_out, int out_size, void* d_ws, size_t ws_size,
                              hipStream_t stream)
{
  const float* z      = (const float*)d_in[0];
  const float* x      = (const float*)d_in[1];
  const float* a      = (const float*)d_in[2];
  const float* pe     = (const float*)d_in[3];
  const float* w_pos1 = (const float*)d_in[4];
  const float* b_pos1 = (const float*)d_in[5];
  const float* w_pos2 = (const float*)d_in[6];
  const float* b_pos2 = (const float*)d_in[7];
  const float* w1     = (const float*)d_in[8];
  const float* b1     = (const float*)d_in[9];
  const float* w2     = (const float*)d_in[10];
  const float* b2     = (const float*)d_in[11];
  const float* w3     = (const float*)d_in[12];
  const float* b3     = (const float*)d_in[13];
  const float* w4     = (const float*)d_in[14];
  const float* b4     = (const float*)d_in[15];
  const float* ln_g   = (const float*)d_in[16];
  const float* ln_b   = (const float*)d_in[17];

  char* ws = (char*)d_ws;
  bf16* pe_bf  = (bf16*)(ws + 0);
  bf16* wp1_bf = (bf16*)(ws + 524288);
  bf16* wp2_bf = (bf16*)(ws + 819200);
  bf16* w1_bf  = (bf16*)(ws + 3178496);
  bf16* w2_bf  = (bf16*)(ws + 7372800);
  bf16* w3_bf  = (bf16*)(ws + 11567104);
  bf16* w4_bf  = (bf16*)(ws + 15761408);
  bf16* h1     = (bf16*)(ws + 19955712);
  bf16* zn_bf  = (bf16*)(ws + 24674304);
  bf16* x_bf   = (bf16*)(ws + 41451520);
  float* wh    = (float*)(ws + 58228736);
  float* cwhz  = (float*)(ws + 66617344);
  bf16*  x1n   = (bf16*)(ws + 66617344);
  bf16*  g     = (bf16*)(ws + 100171776);
  float* x1    = (float*)(ws + 24674304);
  float* out   = (float*)d_out;

  CvtSegs segs;
  segs.src[0] = pe;  segs.src[1] = w_pos1; segs.src[2] = w_pos2;
  segs.src[3] = w1;  segs.src[4] = w2;     segs.src[5] = w3; segs.src[6] = w4;
  int bo[8] = {0, 256, 400, 1552, 3600, 5648, 7696, 9744};
  for (int i = 0; i < 8; ++i) segs.blk_off[i] = bo[i];
  cvt7_k<<<9744, 256, 0, stream>>>(segs, (bf16*)ws);
  cvt_k<<<8192, 256, 0, stream>>>(x, x_bf, 8388608);

  // 1. zn = LN(z) -> bf16
  ln_k<<<8192, 256, 0, stream>>>(z, zn_bf, ln_g, ln_b);
  // 2. h1 = gelu(pe @ w_pos1^T + b_pos1) -> bf16   [2048, 1152], K=128
  //    QCLIP=190: h1 rows > smax+190 feed only skipped step-3 blocks -> skip.
  gemm_k<0, 190><<<dim3(9, 16), 256, 0, stream>>>(pe_bf, wp1_bf, b_pos1, h1, nullptr, a, 2048, 1152, 128);
  // 3. wh = window * (h1 @ w_pos2^T + b_pos2) f32  [2048, 1024], K=1152
  //    QCLIP=63: wh rows > smax+63 are never read by conv_k (window < 1e-9).
  gemmw_k<1, 63><<<dim3(8, 16), 256, 0, stream>>>(h1, wp2_bf, b_pos2, wh, a, nullptr, 2048, 1024, 1152);
  // 4. cwhz = causal depthwise conv(zn, wh) f32    [4, 2048, 1024]
  conv_k<<<dim3(32, 16, 4), 256, 0, stream>>>(zn_bf, wh, a, cwhz);
  // 5. g1 = gelu(x @ w1^T + b1) -> bf16            [8192, 2048], K=1024 (1024 blk = 3/CU)
  gemm_k<0><<<dim3(16, 64), 256, 0, stream>>>(x_bf, w1_bf, b1, g, nullptr, nullptr, 8192, 2048, 1024);
  // 6. x1 = (g1 @ w2^T + b2) * cwhz + z   f32      [8192, 1024], K=2048 (512 blk = 2/CU)
  gemmw_k<2><<<dim3(8, 64), 256, 0, stream>>>(g, w2_bf, b2, x1, cwhz, z, 8192, 1024, 2048);
  // 7. x1n = LN(x1) -> bf16
  ln_k<<<8192, 256, 0, stream>>>(x1, x1n, ln_g, ln_b);
  // 8. g3 = gelu(x1n @ w3^T + b3) -> bf16          [8192, 2048], K=1024
  gemm_k<0><<<dim3(16, 64), 256, 0, stream>>>(x1n, w3_bf, b3, g, nullptr, nullptr, 8192, 2048, 1024);
  // 9. out = (g3 @ w4^T + b4) + x1  f32            [8192, 1024], K=2048
  gemmw_k<3><<<dim3(8, 64), 256, 0, stream>>>(g, w4_bf, b4, out, x1, nullptr, 8192, 1024, 2048);
}

// Round 9
// 414.255 us; speedup vs baseline: 1.2746x; 1.0201x over previous
//
#include <hip/hip_runtime.h>
#include <hip/hip_bf16.h>
#include <cmath>

typedef __hip_bfloat16 bf16;
typedef __attribute__((ext_vector_type(8))) short bf16x8;
typedef __attribute__((ext_vector_type(4))) float f32x4;

static __device__ __forceinline__ float b2f(bf16 v) { return __bfloat162float(v); }
static __device__ __forceinline__ bf16 f2b(float v) { return __float2bfloat16(v); }
static __device__ __forceinline__ float us2f(unsigned short u) {
  return __uint_as_float(((unsigned)u) << 16);
}

static __device__ __forceinline__ void gl2lds16(const bf16* g, bf16* l) {
  __builtin_amdgcn_global_load_lds(
      (const __attribute__((address_space(1))) void*)g,
      (__attribute__((address_space(3))) void*)l, 16, 0, 0);
}

// tanh-form GELU: |err vs erf-form| <~1e-3, far below bf16 rounding of outputs
static __device__ __forceinline__ float gelu_fast(float v) {
  float u = v * (0.7978845608f + 0.0356774081f * v * v);
  float e = __expf(2.f * u);
  return v * (e * __frcp_rn(e + 1.f));
}

// XCD-aware bijective swizzle (m204)
static __device__ __forceinline__ int xcd_swz(int lid, int nwg) {
  const int q = nwg >> 3, r = nwg & 7;
  const int xcd = lid & 7, loc = lid >> 3;
  const int base = (xcd < r) ? xcd * (q + 1) : r * (q + 1) + (xcd - r) * q;
  return base + loc;
}

// ---------------- prep: weight cvt (7 tensors) + x cvt + LN(z), one launch ----------------
struct CvtSegs { const float* src[7]; int blk_off[8]; };
__global__ __launch_bounds__(256) void prep_k(
    CvtSegs s, bf16* __restrict__ dst0,                 // seg A: blocks [0, 9744)
    const float* __restrict__ x, bf16* __restrict__ x_bf, // seg B: [9744, 17936)
    const float* __restrict__ z, bf16* __restrict__ zn,   // seg C: [17936, 26128)
    const float* __restrict__ gamma, const float* __restrict__ beta)
{
  const int b = blockIdx.x, tid = threadIdx.x;
  if (b < 9744) {
    int seg = 0;
#pragma unroll
    for (int i = 0; i < 6; ++i) seg += (b >= s.blk_off[i + 1]) ? 1 : 0;
    const float* src = s.src[seg] + (size_t)(b - s.blk_off[seg]) * 1024;
    bf16* dst = dst0 + (size_t)b * 1024;
    int idx = tid * 4;
    float4 v = *(const float4*)(src + idx);
    union { bf16 bb[4]; ushort4 u; } o;
    o.bb[0] = f2b(v.x); o.bb[1] = f2b(v.y); o.bb[2] = f2b(v.z); o.bb[3] = f2b(v.w);
    *(ushort4*)(dst + idx) = o.u;
  } else if (b < 17936) {
    size_t idx = ((size_t)(b - 9744) * 256 + tid) * 4;
    float4 v = *(const float4*)(x + idx);
    union { bf16 bb[4]; ushort4 u; } o;
    o.bb[0] = f2b(v.x); o.bb[1] = f2b(v.y); o.bb[2] = f2b(v.z); o.bb[3] = f2b(v.w);
    *(ushort4*)(x_bf + idx) = o.u;
  } else {
    __shared__ float red[16];
    const int row = b - 17936;
    float4 v = *(const float4*)(z + (size_t)row * 1024 + tid * 4);
    float sa  = v.x + v.y + v.z + v.w;
    float s2 = v.x * v.x + v.y * v.y + v.z * v.z + v.w * v.w;
#pragma unroll
    for (int m = 32; m; m >>= 1) { sa += __shfl_xor(sa, m, 64); s2 += __shfl_xor(s2, m, 64); }
    const int wid = tid >> 6;
    if ((tid & 63) == 0) { red[wid] = sa; red[wid + 8] = s2; }
    __syncthreads();
    sa = red[0] + red[1] + red[2] + red[3];
    s2 = red[8] + red[9] + red[10] + red[11];
    const float mu  = sa * (1.f / 1024.f);
    const float var = s2 * (1.f / 1024.f) - mu * mu;
    const float rs  = rsqrtf(var + 1e-5f);
    float4 g = *(const float4*)(gamma + tid * 4);
    float4 bt = *(const float4*)(beta + tid * 4);
    union { bf16 bb[4]; ushort4 u; } o;
    o.bb[0] = f2b((v.x - mu) * rs * g.x + bt.x);
    o.bb[1] = f2b((v.y - mu) * rs * g.y + bt.y);
    o.bb[2] = f2b((v.z - mu) * rs * g.z + bt.z);
    o.bb[3] = f2b((v.w - mu) * rs * g.w + bt.w);
    *(ushort4*)(zn + (size_t)row * 1024 + tid * 4) = o.u;
  }
}

// ---------------- LayerNorm over rows of 1024: f32 in, bf16 out (step 7) ----------------
__global__ __launch_bounds__(256) void ln_k(const float* __restrict__ X, bf16* __restrict__ Y,
                                            const float* __restrict__ gamma,
                                            const float* __restrict__ beta)
{
  __shared__ float red[16];
  const int row = blockIdx.x, tid = threadIdx.x;
  float4 v = *(const float4*)(X + (size_t)row * 1024 + tid * 4);
  float s  = v.x + v.y + v.z + v.w;
  float s2 = v.x * v.x + v.y * v.y + v.z * v.z + v.w * v.w;
#pragma unroll
  for (int m = 32; m; m >>= 1) { s += __shfl_xor(s, m, 64); s2 += __shfl_xor(s2, m, 64); }
  const int wid = tid >> 6;
  if ((tid & 63) == 0) { red[wid] = s; red[wid + 8] = s2; }
  __syncthreads();
  s  = red[0] + red[1] + red[2] + red[3];
  s2 = red[8] + red[9] + red[10] + red[11];
  const float mu  = s * (1.f / 1024.f);
  const float var = s2 * (1.f / 1024.f) - mu * mu;
  const float rs  = rsqrtf(var + 1e-5f);
  float4 g = *(const float4*)(gamma + tid * 4);
  float4 bt = *(const float4*)(beta + tid * 4);
  union { bf16 b[4]; ushort4 u; } o;
  o.b[0] = f2b((v.x - mu) * rs * g.x + bt.x);
  o.b[1] = f2b((v.y - mu) * rs * g.y + bt.y);
  o.b[2] = f2b((v.z - mu) * rs * g.z + bt.z);
  o.b[3] = f2b((v.w - mu) * rs * g.w + bt.w);
  *(ushort4*)(Y + (size_t)row * 1024 + tid * 4) = o.u;
}

// ================= GEMM 128x128 BK=32 (4 waves, 3-stage async) — step 8 =================
template<int EPI, int QCLIP = 0>
__global__ __launch_bounds__(256, 3) void gemm_k(
    const bf16* __restrict__ A, const bf16* __restrict__ W,
    const float* __restrict__ bias, void* __restrict__ Out,
    const void* __restrict__ aux0, const void* __restrict__ aux1,
    int M, int N, int K)
{
  __shared__ bf16 As[3][128 * 32];
  __shared__ bf16 Bs[3][128 * 32];
  const int tid = threadIdx.x;
  const int wid = tid >> 6, lane = tid & 63;
  const int quad = lane >> 4, l16 = lane & 15;
  const int wm = wid >> 1, wn = wid & 1;

  const int nwg = gridDim.x * gridDim.y;
  int lid = xcd_swz(blockIdx.y * gridDim.x + blockIdx.x, nwg);
  const int bx = lid % gridDim.x, by = lid / gridDim.x;
  const int m0 = by * 128, n0 = bx * 128;

  if (QCLIP > 0) {
    const float smax = 20.7f / __expf(((const float*)aux1)[0]);
    if ((float)(m0 - QCLIP) > smax) return;
  }

  f32x4 acc[4][4];
#pragma unroll
  for (int i = 0; i < 4; ++i)
#pragma unroll
    for (int j = 0; j < 4; ++j) acc[i][j] = (f32x4){0.f, 0.f, 0.f, 0.f};

  const bf16 *ga[2], *gb[2];
  int ldso[2];
#pragma unroll
  for (int r = 0; r < 2; ++r) {
    int p = r * 256 + wid * 64 + lane;
    int row = p >> 2;
    int sko = ((p & 3) ^ ((p >> 3) & 3)) << 3;
    ga[r] = A + (size_t)(m0 + row) * K + sko;
    gb[r] = W + (size_t)(n0 + row) * K + sko;
    ldso[r] = (r * 256 + wid * 64) * 8;
  }
  int apos[4], bpos[4];
#pragma unroll
  for (int i = 0; i < 4; ++i) {
    int ar = wm * 64 + i * 16 + l16;
    apos[i] = (ar * 4 + (quad ^ ((ar >> 1) & 3))) * 8;
    int br = wn * 64 + i * 16 + l16;
    bpos[i] = (br * 4 + (quad ^ ((br >> 1) & 3))) * 8;
  }

  const int niter = K >> 5;
#pragma unroll
  for (int t = 0; t < 2; ++t)
#pragma unroll
    for (int r = 0; r < 2; ++r) {
      gl2lds16(ga[r] + t * 32, &As[t][ldso[r]]);
      gl2lds16(gb[r] + t * 32, &Bs[t][ldso[r]]);
    }

  int cur = 0;
  for (int k = 0; k < niter; ++k) {
    if (k == niter - 1) { asm volatile("s_waitcnt vmcnt(0)" ::: "memory"); }
    else               { asm volatile("s_waitcnt vmcnt(4)" ::: "memory"); }
    asm volatile("s_barrier" ::: "memory");

    const bf16* as = As[cur];
    const bf16* bs = Bs[cur];
    bf16x8 af[4], bfr[4];
#pragma unroll
    for (int i = 0; i < 4; ++i) af[i]  = *(const bf16x8*)(as + apos[i]);
#pragma unroll
    for (int j = 0; j < 4; ++j) bfr[j] = *(const bf16x8*)(bs + bpos[j]);
    asm volatile("s_waitcnt lgkmcnt(0)" ::: "memory");

    if (k + 2 < niter) {
      int nb = cur + 2; if (nb >= 3) nb -= 3;
#pragma unroll
      for (int r = 0; r < 2; ++r) {
        gl2lds16(ga[r] + (k + 2) * 32, &As[nb][ldso[r]]);
        gl2lds16(gb[r] + (k + 2) * 32, &Bs[nb][ldso[r]]);
      }
    }
#pragma unroll
    for (int i = 0; i < 4; ++i)
#pragma unroll
      for (int j = 0; j < 4; ++j)
        acc[i][j] = __builtin_amdgcn_mfma_f32_16x16x32_bf16(af[i], bfr[j], acc[i][j], 0, 0, 0);
    cur += 1; if (cur == 3) cur = 0;
  }

  float expa = 0.f;
  if (EPI == 1) expa = expf(((const float*)aux0)[0]);
#pragma unroll
  for (int i = 0; i < 4; ++i) {
    const int gm_base = m0 + wm * 64 + i * 16 + quad * 4;
#pragma unroll
    for (int j = 0; j < 4; ++j) {
      const int gn = n0 + wn * 64 + j * 16 + l16;
      const float bv = bias[gn];
#pragma unroll
      for (int r = 0; r < 4; ++r) {
        const int gm = gm_base + r;
        const size_t off = (size_t)gm * N + gn;
        float v = acc[i][j][r] + bv;
        if (EPI == 0) ((bf16*)Out)[off] = f2b(gelu_fast(v));
        else if (EPI == 1) ((float*)Out)[off] = v * expf(-(float)gm * expa);
        else if (EPI == 2) ((float*)Out)[off] = v * ((const float*)aux0)[off] + ((const float*)aux1)[off];
        else ((float*)Out)[off] = v + ((const float*)aux0)[off];
      }
    }
  }
}

// ===== merged step5 + step2 (both gelu->bf16): blocks [0,1024) = step5, [1024,1168) = step2 =====
// Step 2 (144 blocks, 0.56/CU standalone = latency-bound) rides step 5's tail.
// Independent: step5 reads x_bf/w1, step2 reads pe_bf/wp1; h1 not read in this launch.
__global__ __launch_bounds__(256, 3) void gemm52_k(
    const bf16* __restrict__ A5, const bf16* __restrict__ W5,
    const float* __restrict__ b5, bf16* __restrict__ O5,
    const bf16* __restrict__ A2, const bf16* __restrict__ W2,
    const float* __restrict__ b2, bf16* __restrict__ O2,
    const float* __restrict__ a)
{
  __shared__ bf16 As[3][128 * 32];
  __shared__ bf16 Bs[3][128 * 32];
  const int tid = threadIdx.x;
  const int wid = tid >> 6, lane = tid & 63;
  const int quad = lane >> 4, l16 = lane & 15;
  const int wm = wid >> 1, wn = wid & 1;

  const bf16 *A, *W;
  const float* bias;
  bf16* Out;
  int N, K, m0, n0;
  if (blockIdx.x < 1024) {           // step 5: [8192,2048] K=1024, grid 16x64
    int lid = xcd_swz(blockIdx.x, 1024);
    m0 = (lid / 16) * 128; n0 = (lid % 16) * 128;
    A = A5; W = W5; bias = b5; Out = O5; N = 2048; K = 1024;
  } else {                            // step 2: [2048,1152] K=128, grid 9x16, QCLIP=190
    int lid = xcd_swz(blockIdx.x - 1024, 144);
    m0 = (lid / 9) * 128; n0 = (lid % 9) * 128;
    A = A2; W = W2; bias = b2; Out = O2; N = 1152; K = 128;
    const float smax = 20.7f / __expf(a[0]);
    if ((float)(m0 - 190) > smax) return;
  }

  f32x4 acc[4][4];
#pragma unroll
  for (int i = 0; i < 4; ++i)
#pragma unroll
    for (int j = 0; j < 4; ++j) acc[i][j] = (f32x4){0.f, 0.f, 0.f, 0.f};

  const bf16 *ga[2], *gb[2];
  int ldso[2];
#pragma unroll
  for (int r = 0; r < 2; ++r) {
    int p = r * 256 + wid * 64 + lane;
    int row = p >> 2;
    int sko = ((p & 3) ^ ((p >> 3) & 3)) << 3;
    ga[r] = A + (size_t)(m0 + row) * K + sko;
    gb[r] = W + (size_t)(n0 + row) * K + sko;
    ldso[r] = (r * 256 + wid * 64) * 8;
  }
  int apos[4], bpos[4];
#pragma unroll
  for (int i = 0; i < 4; ++i) {
    int ar = wm * 64 + i * 16 + l16;
    apos[i] = (ar * 4 + (quad ^ ((ar >> 1) & 3))) * 8;
    int br = wn * 64 + i * 16 + l16;
    bpos[i] = (br * 4 + (quad ^ ((br >> 1) & 3))) * 8;
  }

  const int niter = K >> 5;
#pragma unroll
  for (int t = 0; t < 2; ++t)
#pragma unroll
    for (int r = 0; r < 2; ++r) {
      gl2lds16(ga[r] + t * 32, &As[t][ldso[r]]);
      gl2lds16(gb[r] + t * 32, &Bs[t][ldso[r]]);
    }

  int cur = 0;
  for (int k = 0; k < niter; ++k) {
    if (k == niter - 1) { asm volatile("s_waitcnt vmcnt(0)" ::: "memory"); }
    else               { asm volatile("s_waitcnt vmcnt(4)" ::: "memory"); }
    asm volatile("s_barrier" ::: "memory");

    const bf16* as = As[cur];
    const bf16* bs = Bs[cur];
    bf16x8 af[4], bfr[4];
#pragma unroll
    for (int i = 0; i < 4; ++i) af[i]  = *(const bf16x8*)(as + apos[i]);
#pragma unroll
    for (int j = 0; j < 4; ++j) bfr[j] = *(const bf16x8*)(bs + bpos[j]);
    asm volatile("s_waitcnt lgkmcnt(0)" ::: "memory");

    if (k + 2 < niter) {
      int nb = cur + 2; if (nb >= 3) nb -= 3;
#pragma unroll
      for (int r = 0; r < 2; ++r) {
        gl2lds16(ga[r] + (k + 2) * 32, &As[nb][ldso[r]]);
        gl2lds16(gb[r] + (k + 2) * 32, &Bs[nb][ldso[r]]);
      }
    }
#pragma unroll
    for (int i = 0; i < 4; ++i)
#pragma unroll
      for (int j = 0; j < 4; ++j)
        acc[i][j] = __builtin_amdgcn_mfma_f32_16x16x32_bf16(af[i], bfr[j], acc[i][j], 0, 0, 0);
    cur += 1; if (cur == 3) cur = 0;
  }

#pragma unroll
  for (int i = 0; i < 4; ++i) {
    const int gm_base = m0 + wm * 64 + i * 16 + quad * 4;
#pragma unroll
    for (int j = 0; j < 4; ++j) {
      const int gn = n0 + wn * 64 + j * 16 + l16;
      const float bv = bias[gn];
#pragma unroll
      for (int r = 0; r < 4; ++r) {
        const size_t off = (size_t)(gm_base + r) * N + gn;
        Out[off] = f2b(gelu_fast(acc[i][j][r] + bv));
      }
    }
  }
}

// ========== GEMM 128x128 BK=64 (4 waves, 2-slot, stage-early) — steps 3,6,9 ==========
template<int EPI, int QCLIP = 0>
__global__ __launch_bounds__(256, 2) void gemmw_k(
    const bf16* __restrict__ A, const bf16* __restrict__ W,
    const float* __restrict__ bias, void* __restrict__ Out,
    const void* __restrict__ aux0, const void* __restrict__ aux1,
    int M, int N, int K)
{
  __shared__ bf16 As[2][128 * 64];
  __shared__ bf16 Bs[2][128 * 64];
  const int tid = threadIdx.x;
  const int wid = tid >> 6, lane = tid & 63;
  const int quad = lane >> 4, l16 = lane & 15;
  const int wm = wid >> 1, wn = wid & 1;

  const int nwg = gridDim.x * gridDim.y;
  int lid = xcd_swz(blockIdx.y * gridDim.x + blockIdx.x, nwg);
  const int bx = lid % gridDim.x, by = lid / gridDim.x;
  const int m0 = by * 128, n0 = bx * 128;

  if (QCLIP > 0) {
    const float smax = 20.7f / __expf(((const float*)aux0)[0]);
    if ((float)(m0 - QCLIP) > smax) return;
  }

  f32x4 acc[4][4];
#pragma unroll
  for (int i = 0; i < 4; ++i)
#pragma unroll
    for (int j = 0; j < 4; ++j) acc[i][j] = (f32x4){0.f, 0.f, 0.f, 0.f};

  const bf16 *ga[4], *gb[4];
  int ldso[4];
#pragma unroll
  for (int r = 0; r < 4; ++r) {
    int p = r * 256 + tid;
    int row = p >> 3;
    int c = (p & 7) ^ (row & 7);
    ga[r] = A + (size_t)(m0 + row) * K + c * 8;
    gb[r] = W + (size_t)(n0 + row) * K + c * 8;
    ldso[r] = p * 8;
  }
  int apos[4][2], bpos[4][2];
#pragma unroll
  for (int i = 0; i < 4; ++i) {
    int ar = wm * 64 + i * 16 + l16;
    int br = wn * 64 + i * 16 + l16;
#pragma unroll
    for (int ks = 0; ks < 2; ++ks) {
      apos[i][ks] = ar * 64 + (((quad + 4 * ks) ^ (ar & 7)) * 8);
      bpos[i][ks] = br * 64 + (((quad + 4 * ks) ^ (br & 7)) * 8);
    }
  }

  const int niter = K >> 6;

#pragma unroll
  for (int r = 0; r < 4; ++r) {
    gl2lds16(ga[r], &As[0][ldso[r]]);
    gl2lds16(gb[r], &Bs[0][ldso[r]]);
  }

  for (int k = 0; k < niter; ++k) {
    asm volatile("s_waitcnt vmcnt(0)" ::: "memory");
    asm volatile("s_barrier" ::: "memory");
    const int cur = k & 1;
    if (k + 1 < niter) {
      const int nxt = cur ^ 1;
#pragma unroll
      for (int r = 0; r < 4; ++r) {
        gl2lds16(ga[r] + (k + 1) * 64, &As[nxt][ldso[r]]);
        gl2lds16(gb[r] + (k + 1) * 64, &Bs[nxt][ldso[r]]);
      }
    }
    const bf16* as = As[cur];
    const bf16* bs = Bs[cur];
    bf16x8 af[4][2], bfr[4][2];
#pragma unroll
    for (int i = 0; i < 4; ++i)
#pragma unroll
      for (int ks = 0; ks < 2; ++ks) af[i][ks] = *(const bf16x8*)(as + apos[i][ks]);
#pragma unroll
    for (int j = 0; j < 4; ++j)
#pragma unroll
      for (int ks = 0; ks < 2; ++ks) bfr[j][ks] = *(const bf16x8*)(bs + bpos[j][ks]);
    asm volatile("s_waitcnt lgkmcnt(0)" ::: "memory");

#pragma unroll
    for (int ks = 0; ks < 2; ++ks)
#pragma unroll
      for (int i = 0; i < 4; ++i)
#pragma unroll
        for (int j = 0; j < 4; ++j)
          acc[i][j] = __builtin_amdgcn_mfma_f32_16x16x32_bf16(af[i][ks], bfr[j][ks], acc[i][j], 0, 0, 0);
  }

  float expa = 0.f;
  if (EPI == 1) expa = expf(((const float*)aux0)[0]);
#pragma unroll
  for (int i = 0; i < 4; ++i) {
    const int gm_base = m0 + wm * 64 + i * 16 + quad * 4;
#pragma unroll
    for (int j = 0; j < 4; ++j) {
      const int gn = n0 + wn * 64 + j * 16 + l16;
      const float bv = bias[gn];
#pragma unroll
      for (int r = 0; r < 4; ++r) {
        const int gm = gm_base + r;
        const size_t off = (size_t)gm * N + gn;
        float v = acc[i][j][r] + bv;
        if (EPI == 0) ((bf16*)Out)[off] = f2b(gelu_fast(v));
        else if (EPI == 1) ((float*)Out)[off] = v * expf(-(float)gm * expa);
        else if (EPI == 2) ((float*)Out)[off] = v * ((const float*)aux0)[off] + ((const float*)aux1)[off];
        else ((float*)Out)[off] = v + ((const float*)aux0)[off];
      }
    }
  }
}

// ---------------- causal depthwise conv (circular-buffer window: no reg shifts) ----------------
__global__ __launch_bounds__(256) void conv_k(
    const bf16* __restrict__ zn,    // [B, L, D] bf16
    const float* __restrict__ wh,   // [L, D] f32
    const float* __restrict__ a,
    float* __restrict__ out)        // [B, L, D] f32
{
  __shared__ float whs[64 * 64];
  __shared__ float znt[128 * 64];   // row r holds u = t0 - sb - 64 + r
  const int tid = threadIdx.x;
  const int dd = tid & 63, ttg = tid >> 6;
  const int t0 = blockIdx.x * 64, d0 = blockIdx.y * 64, b = blockIdx.z;
  const float expa = expf(a[0]);
  const float smax = 20.7f / expa;
  const unsigned short* znu = (const unsigned short*)zn;

  float acc[16];
#pragma unroll
  for (int q = 0; q < 16; ++q) acc[q] = 0.f;

  for (int sb = 0; sb <= t0 + 63; sb += 64) {
    if ((float)sb > smax) break;
    float4 wv4[4];
#pragma unroll
    for (int i = 0; i < 4; ++i) {
      int cc = tid + 256 * i;
      int row = cc >> 4, dq = (cc & 15) * 4;
      wv4[i] = *(const float4*)&wh[(size_t)(sb + row) * 1024 + d0 + dq];
    }
    ushort4 zv4[8];
#pragma unroll
    for (int i = 0; i < 8; ++i) {
      int cc = tid + 256 * i;
      int row = cc >> 4, dq = (cc & 15) * 4;
      int u = t0 - sb - 64 + row;
      zv4[i] = (u >= 0) ? *(const ushort4*)&znu[((size_t)b * 2048 + u) * 1024 + d0 + dq]
                        : make_ushort4(0, 0, 0, 0);
    }
#pragma unroll
    for (int i = 0; i < 4; ++i) {
      int cc = tid + 256 * i;
      *(float4*)&whs[(cc >> 4) * 64 + (cc & 15) * 4] = wv4[i];
    }
#pragma unroll
    for (int i = 0; i < 8; ++i) {
      int cc = tid + 256 * i;
      float4 o;
      o.x = us2f(zv4[i].x); o.y = us2f(zv4[i].y); o.z = us2f(zv4[i].z); o.w = us2f(zv4[i].w);
      *(float4*)&znt[(cc >> 4) * 64 + (cc & 15) * 4] = o;
    }
    __syncthreads();

    // circular window: slot (q-ss)&15 holds znt row ttg*16+q+64-ss.
    // Full unroll -> all indices compile-time (rule 20); replaces 15 moves/tap.
    float win[16];
#pragma unroll
    for (int r = 0; r < 16; ++r) win[r] = znt[(ttg * 16 + r + 64) * 64 + dd];
#pragma unroll
    for (int ss = 0; ss < 64; ++ss) {
      float wv = whs[ss * 64 + dd];
#pragma unroll
      for (int q = 0; q < 16; ++q) acc[q] += wv * win[(q - ss) & 15];
      if (ss < 63) win[(15 - ss) & 15] = znt[(ttg * 16 + 63 - ss) * 64 + dd];
    }
    __syncthreads();
  }
#pragma unroll
  for (int q = 0; q < 16; ++q) {
    int t = t0 + ttg * 16 + q;
    out[((size_t)b * 2048 + t) * 1024 + d0 + dd] = acc[q];
  }
}

extern "C" void kernel_launch(void* const* d_in, const int* in_sizes, int n_in,
                              void* d_out, int out_size, void* d_ws, size_t ws_size,
                              hipStream_t stream)
{
  const float* z      = (const float*)d_in[0];
  const float* x      = (const float*)d_in[1];
  const float* a      = (const float*)d_in[2];
  const float* pe     = (const float*)d_in[3];
  const float* w_pos1 = (const float*)d_in[4];
  const float* b_pos1 = (const float*)d_in[5];
  const float* w_pos2 = (const float*)d_in[6];
  const float* b_pos2 = (const float*)d_in[7];
  const float* w1     = (const float*)d_in[8];
  const float* b1     = (const float*)d_in[9];
  const float* w2     = (const float*)d_in[10];
  const float* b2     = (const float*)d_in[11];
  const float* w3     = (const float*)d_in[12];
  const float* b3     = (const float*)d_in[13];
  const float* w4     = (const float*)d_in[14];
  const float* b4     = (const float*)d_in[15];
  const float* ln_g   = (const float*)d_in[16];
  const float* ln_b   = (const float*)d_in[17];

  char* ws = (char*)d_ws;
  bf16* pe_bf  = (bf16*)(ws + 0);
  bf16* wp1_bf = (bf16*)(ws + 524288);
  bf16* wp2_bf = (bf16*)(ws + 819200);
  bf16* w1_bf  = (bf16*)(ws + 3178496);
  bf16* w2_bf  = (bf16*)(ws + 7372800);
  bf16* w3_bf  = (bf16*)(ws + 11567104);
  bf16* w4_bf  = (bf16*)(ws + 15761408);
  bf16* h1     = (bf16*)(ws + 19955712);
  bf16* zn_bf  = (bf16*)(ws + 24674304);
  bf16* x_bf   = (bf16*)(ws + 41451520);
  float* wh    = (float*)(ws + 58228736);
  float* cwhz  = (float*)(ws + 66617344);
  bf16*  x1n   = (bf16*)(ws + 66617344);
  bf16*  g     = (bf16*)(ws + 100171776);
  float* x1    = (float*)(ws + 24674304);
  float* out   = (float*)d_out;

  CvtSegs segs;
  segs.src[0] = pe;  segs.src[1] = w_pos1; segs.src[2] = w_pos2;
  segs.src[3] = w1;  segs.src[4] = w2;     segs.src[5] = w3; segs.src[6] = w4;
  int bo[8] = {0, 256, 400, 1552, 3600, 5648, 7696, 9744};
  for (int i = 0; i < 8; ++i) segs.blk_off[i] = bo[i];

  // 0. prep: weight cvts + x cvt + LN(z)  (3 launches -> 1)
  prep_k<<<26128, 256, 0, stream>>>(segs, (bf16*)ws, x, x_bf, z, zn_bf, ln_g, ln_b);
  // 5+2 merged: g1 = gelu(x @ w1^T + b1) [blocks 0-1023] and
  //             h1 = gelu(pe @ w_pos1^T + b_pos1) [blocks 1024-1167, QCLIP'd]
  gemm52_k<<<1168, 256, 0, stream>>>(x_bf, w1_bf, b1, g, pe_bf, wp1_bf, b_pos1, h1, a);
  // 3. wh = window * (h1 @ w_pos2^T + b_pos2) f32  [2048, 1024], K=1152, QCLIP=63
  gemmw_k<1, 63><<<dim3(8, 16), 256, 0, stream>>>(h1, wp2_bf, b_pos2, wh, a, nullptr, 2048, 1024, 1152);
  // 4. cwhz = causal depthwise conv(zn, wh) f32    [4, 2048, 1024]
  conv_k<<<dim3(32, 16, 4), 256, 0, stream>>>(zn_bf, wh, a, cwhz);
  // 6. x1 = (g1 @ w2^T + b2) * cwhz + z   f32      [8192, 1024], K=2048
  gemmw_k<2><<<dim3(8, 64), 256, 0, stream>>>(g, w2_bf, b2, x1, cwhz, z, 8192, 1024, 2048);
  // 7. x1n = LN(x1) -> bf16
  ln_k<<<8192, 256, 0, stream>>>(x1, x1n, ln_g, ln_b);
  // 8. g3 = gelu(x1n @ w3^T + b3) -> bf16          [8192, 2048], K=1024
  gemm_k<0><<<dim3(16, 64), 256, 0, stream>>>(x1n, w3_bf, b3, g, nullptr, nullptr, 8192, 2048, 1024);
  // 9. out = (g3 @ w4^T + b4) + x1  f32            [8192, 1024], K=2048
  gemmw_k<3><<<dim3(8, 64), 256, 0, stream>>>(g, w4_bf, b4, out, x1, nullptr, 8192, 1024, 2048);
}